// Round 2
// baseline (647.043 us; speedup 1.0000x reference)
//
#include <hip/hip_runtime.h>
#include <hip/hip_bf16.h>

#define LSEQ 2048
#define BATCH 2
#define KNB 48

typedef unsigned long long u64;

__device__ __forceinline__ u64 umin64(u64 a, u64 b) { return a < b ? a : b; }

// Compute the 5-atom X_all row (atoms 0..3 + virtual atom) for one token.
// base = (b*LSEQ + l) * 14 * 3 (float index of atom 0, coord 0)
__device__ __forceinline__ void compute_token_atoms(const float* __restrict__ X,
                                                    long base, float* dst) {
    float a[12];
#pragma unroll
    for (int i = 0; i < 12; ++i) a[i] = X[base + i];  // atoms 0..3
    // Xc = atom1, X1 = atom0, X2 = atom2  (VIRT_SLOTS = [1,0,2])
    float cx = a[3], cy = a[4], cz = a[5];
    float b1x = a[0] - cx, b1y = a[1] - cy, b1z = a[2] - cz;
    float b2x = a[6] - cx, b2y = a[7] - cy, b2z = a[8] - cz;
    float nx = b1y * b2z - b1z * b2y;
    float ny = b1z * b2x - b1x * b2z;
    float nz = b1x * b2y - b1y * b2x;
    const float WN = 0.58273431f, WB1 = -0.56802827f, WB2 = -0.54067466f;
#pragma unroll
    for (int i = 0; i < 12; ++i) dst[i] = a[i];
    dst[12] = WN * nx + WB1 * b1x + WB2 * b2x + cx;
    dst[13] = WN * ny + WB1 * b1y + WB2 * b2y + cy;
    dst[14] = WN * nz + WB1 * b1z + WB2 * b2z + cz;
}

// One block per (b, i): compute D row, select 48 nearest (tie-break lower idx).
__global__ __launch_bounds__(256) void topk_kernel(const float* __restrict__ X,
                                                   const float* __restrict__ Xm,
                                                   int* __restrict__ idx_ws,
                                                   float* __restrict__ out_idx) {
    __shared__ float ds[LSEQ];
    __shared__ u64 red[256];
    const int row = blockIdx.x;  // b*LSEQ + i
    const int b = row >> 11;
    const int t = threadIdx.x;

    const long cbase = (long)row * 42 + 3;  // atom 1
    const float xi0 = X[cbase], xi1 = X[cbase + 1], xi2 = X[cbase + 2];
    const float mi = Xm[(long)row * 14 + 1];
    const long b0 = (long)b * LSEQ;

    for (int j = t; j < LSEQ; j += 256) {
        long jb = (b0 + j) * 42 + 3;
        float dx = xi0 - X[jb];
        float dy = xi1 - X[jb + 1];
        float dz = xi2 - X[jb + 2];
        // match numpy rounding exactly: ((dx^2 + dy^2) + dz^2) + 1e-6, no fma
        float d2 = __fadd_rn(__fadd_rn(__fmul_rn(dx, dx), __fmul_rn(dy, dy)),
                             __fmul_rn(dz, dz));
        float D = sqrtf(__fadd_rn(d2, 1e-6f));
        float mj = Xm[(b0 + j) * 14 + 1];
        ds[j] = D + (1.0f - mi * mj) * 1000000.0f;
    }
    __syncthreads();

    for (int it = 0; it < KNB; ++it) {
        u64 best = ~0ULL;
        for (int j = t; j < LSEQ; j += 256) {
            u64 key = ((u64)__float_as_uint(ds[j]) << 32) | (unsigned)j;
            best = umin64(best, key);
        }
        red[t] = best;
        __syncthreads();
        if (t < 64) {
            u64 v = red[t];
            v = umin64(v, red[t + 64]);
            v = umin64(v, red[t + 128]);
            v = umin64(v, red[t + 192]);
#pragma unroll
            for (int off = 32; off > 0; off >>= 1) {
                u64 o = __shfl_down(v, off);
                v = umin64(v, o);
            }
            if (t == 0) red[0] = v;
        }
        __syncthreads();
        int widx = (int)(red[0] & 0xffffffffu);
        if (t == 0) {
            idx_ws[row * KNB + it] = widx;
            out_idx[(long)row * KNB + it] = (float)widx;
            ds[widx] = 3.0e38f;  // remove from further consideration
        }
        __syncthreads();
    }
}

// One block per (b, i, kb): 16 edges, 128 output channels.
__global__ __launch_bounds__(128) void edge_kernel(
    const float* __restrict__ X, const int* __restrict__ ridx,
    const float* __restrict__ posW, const float* __restrict__ posb,
    const float* __restrict__ edgeW, const float* __restrict__ gamma,
    const float* __restrict__ beta, const int* __restrict__ idx_ws,
    float* __restrict__ outE) {
    __shared__ float xi[15];
    __shared__ float xj[16][15];
    __shared__ int dclip[16];
    __shared__ float Dp[16][25];
    __shared__ float feat[16][416];
    __shared__ float ps[8][16], ps2[8][16];
    __shared__ float mean_s[16], scale_s[16];

    const int blk = blockIdx.x;
    const int row = blk / 3;  // b*LSEQ + i
    const int kb = blk % 3;
    const int b = row >> 11;
    const int t = threadIdx.x;

    if (t < 16) {
        int e = t;
        int j = idx_ws[row * KNB + kb * 16 + e];
        int off = ridx[row] - ridx[b * LSEQ + j] + 32;
        off = off < 0 ? 0 : (off > 64 ? 64 : off);
        dclip[e] = off;
        compute_token_atoms(X, (long)(b * LSEQ + j) * 42, xj[e]);
    } else if (t == 16) {
        compute_token_atoms(X, (long)row * 42, xi);
    }
    __syncthreads();

    // 16 edges x 25 atom-pair distances
    for (int idx = t; idx < 16 * 25; idx += 128) {
        int e = idx / 25, pq = idx % 25;
        int ai = pq / 5, aj = pq % 5;
        float dx = xi[ai * 3 + 0] - xj[e][aj * 3 + 0];
        float dy = xi[ai * 3 + 1] - xj[e][aj * 3 + 1];
        float dz = xi[ai * 3 + 2] - xj[e][aj * 3 + 2];
        float d2 = (dx * dx + dy * dy) + dz * dz;
        Dp[e][pq] = sqrtf(d2 + 1e-6f);
    }
    __syncthreads();

    // 416 features per edge: [16 pos | 400 rbf]
    const float inv_sigma = 1.0f / 1.25f;
#pragma unroll 1
    for (int e = 0; e < 16; ++e) {
        for (int f = t; f < 416; f += 128) {
            float v;
            if (f < 16) {
                v = posW[dclip[e] * 16 + f] + posb[f];
            } else {
                int p = (f - 16) >> 4, r = (f - 16) & 15;
                float mu = 2.0f + (20.0f / 15.0f) * (float)r;
                float x = (Dp[e][p] - mu) * inv_sigma;
                v = __expf(-x * x);
            }
            feat[e][f] = v;
        }
    }
    __syncthreads();

    // matvec: each thread owns channel c=t for all 16 edges
    float acc[16];
#pragma unroll
    for (int e = 0; e < 16; ++e) acc[e] = 0.0f;
    for (int f = 0; f < 416; ++f) {
        float w = edgeW[f * 128 + t];
#pragma unroll
        for (int e = 0; e < 16; ++e) acc[e] = fmaf(feat[e][f], w, acc[e]);
    }
    __syncthreads();

    // LayerNorm over 128 channels per edge; reuse feat LDS (stride 129 to
    // spread banks)
    float* lacc = &feat[0][0];
#pragma unroll
    for (int e = 0; e < 16; ++e) lacc[e * 129 + t] = acc[e];
    __syncthreads();
    {
        int g = t >> 4, e2 = t & 15;
        float s = 0.0f, s2 = 0.0f;
        for (int c0 = g * 16; c0 < g * 16 + 16; ++c0) {
            float v = lacc[e2 * 129 + c0];
            s += v;
            s2 = fmaf(v, v, s2);
        }
        ps[g][e2] = s;
        ps2[g][e2] = s2;
    }
    __syncthreads();
    if (t < 16) {
        float S = 0.0f, S2 = 0.0f;
#pragma unroll
        for (int gg = 0; gg < 8; ++gg) {
            S += ps[gg][t];
            S2 += ps2[gg][t];
        }
        float m = S * (1.0f / 128.0f);
        float var = S2 * (1.0f / 128.0f) - m * m;
        mean_s[t] = m;
        scale_s[t] = rsqrtf(var + 1e-5f);
    }
    __syncthreads();

    float gmv = gamma[t], btv = beta[t];
    long base = ((long)row * KNB + kb * 16) * 128;
#pragma unroll
    for (int e = 0; e < 16; ++e) {
        float val = (acc[e] - mean_s[e]) * scale_s[e] * gmv + btv;
        outE[base + e * 128 + t] = val;
    }
}

extern "C" void kernel_launch(void* const* d_in, const int* in_sizes, int n_in,
                              void* d_out, int out_size, void* d_ws, size_t ws_size,
                              hipStream_t stream) {
    const float* X = (const float*)d_in[0];
    const float* Xm = (const float*)d_in[1];
    // d_in[2] = S : dead input (slot tables are token-independent)
    const int* ridx = (const int*)d_in[3];
    const float* posW = (const float*)d_in[4];
    const float* posb = (const float*)d_in[5];
    const float* edgeW = (const float*)d_in[6];
    const float* gamma = (const float*)d_in[7];
    const float* beta = (const float*)d_in[8];

    float* out = (float*)d_out;
    const long E_elems = (long)BATCH * LSEQ * KNB * 128;  // 25,165,824
    float* out_idx = out + E_elems;
    int* idx_ws = (int*)d_ws;  // exact int32 E_idx for edge_kernel

    topk_kernel<<<BATCH * LSEQ, 256, 0, stream>>>(X, Xm, idx_ws, out_idx);
    edge_kernel<<<BATCH * LSEQ * 3, 128, 0, stream>>>(X, ridx, posW, posb, edgeW,
                                                      gamma, beta, idx_ws, out);
}

// Round 3
// 280.928 us; speedup vs baseline: 2.3032x; 2.3032x over previous
//
#include <hip/hip_runtime.h>
#include <hip/hip_bf16.h>

#define LSEQ 2048
#define BATCH 2
#define KNB 48
#define FPAD 440   // feat row pad (bf16 elems): 880B stride -> <=2-way LDS conflict
#define CPAD 130   // acc row pad (f32)

typedef unsigned long long u64;
typedef __attribute__((ext_vector_type(8))) short short8;
typedef __attribute__((ext_vector_type(4))) float f32x4;

__device__ __forceinline__ u64 umin64(u64 a, u64 b) { return a < b ? a : b; }

// 5-atom X_all row (atoms 0..3 + virtual). base = float index of atom0.x
__device__ __forceinline__ void compute_token_atoms(const float* __restrict__ X,
                                                    long base, float* dst) {
    float a[12];
#pragma unroll
    for (int i = 0; i < 12; ++i) a[i] = X[base + i];
    // Xc = atom1, X1 = atom0, X2 = atom2  (VIRT_SLOTS = [1,0,2])
    float cx = a[3], cy = a[4], cz = a[5];
    float b1x = a[0] - cx, b1y = a[1] - cy, b1z = a[2] - cz;
    float b2x = a[6] - cx, b2y = a[7] - cy, b2z = a[8] - cz;
    float nx = b1y * b2z - b1z * b2y;
    float ny = b1z * b2x - b1x * b2z;
    float nz = b1x * b2y - b1y * b2x;
    const float WN = 0.58273431f, WB1 = -0.56802827f, WB2 = -0.54067466f;
#pragma unroll
    for (int i = 0; i < 12; ++i) dst[i] = a[i];
    dst[12] = WN * nx + WB1 * b1x + WB2 * b2x + cx;
    dst[13] = WN * ny + WB1 * b1y + WB2 * b2y + cy;
    dst[14] = WN * nz + WB1 * b1z + WB2 * b2z + cz;
}

// Pack edgeW (416x128 f32) into MFMA B-fragment order, bf16.
// Fragment (n,s): lane l, j=0..7 -> B[k=s*32+(l>>4)*8+j][col=n*16+(l&15)]
__global__ __launch_bounds__(64) void pack_w_kernel(const float* __restrict__ edgeW,
                                                    short8* __restrict__ Bp) {
    int blk = blockIdx.x;  // n*13 + s, 0..103
    int l = threadIdx.x;
    int col = ((blk / 13) * 16) + (l & 15);
    int k0 = (blk % 13) * 32 + (l >> 4) * 8;
    union { short8 v; __hip_bfloat16 h[8]; } u;
#pragma unroll
    for (int j = 0; j < 8; ++j)
        u.h[j] = __float2bfloat16(edgeW[(k0 + j) * 128 + col]);
    Bp[(long)blk * 64 + l] = u.v;
}

// One block per (b, i): D row + iterative 48-min selection (tie: lower idx).
__global__ __launch_bounds__(256) void topk_kernel(const float* __restrict__ X,
                                                   const float* __restrict__ Xm,
                                                   int* __restrict__ idx_ws,
                                                   float* __restrict__ out_idx) {
    __shared__ float ds[LSEQ];
    __shared__ u64 red[256];
    const int row = blockIdx.x;
    const int b = row >> 11;
    const int t = threadIdx.x;

    const long cbase = (long)row * 42 + 3;  // atom 1
    const float xi0 = X[cbase], xi1 = X[cbase + 1], xi2 = X[cbase + 2];
    const float mi = Xm[(long)row * 14 + 1];
    const long b0 = (long)b * LSEQ;

    for (int j = t; j < LSEQ; j += 256) {
        long jb = (b0 + j) * 42 + 3;
        float dx = xi0 - X[jb];
        float dy = xi1 - X[jb + 1];
        float dz = xi2 - X[jb + 2];
        // match numpy exactly: ((dx^2+dy^2)+dz^2)+1e-6, no fma contraction
        float d2 = __fadd_rn(__fadd_rn(__fmul_rn(dx, dx), __fmul_rn(dy, dy)),
                             __fmul_rn(dz, dz));
        float D = sqrtf(__fadd_rn(d2, 1e-6f));
        float mj = Xm[(b0 + j) * 14 + 1];
        ds[j] = D + (1.0f - mi * mj) * 1000000.0f;
    }
    __syncthreads();

    for (int it = 0; it < KNB; ++it) {
        u64 best = ~0ULL;
        for (int j = t; j < LSEQ; j += 256) {
            u64 key = ((u64)__float_as_uint(ds[j]) << 32) | (unsigned)j;
            best = umin64(best, key);
        }
        red[t] = best;
        __syncthreads();
        if (t < 64) {
            u64 v = red[t];
            v = umin64(v, red[t + 64]);
            v = umin64(v, red[t + 128]);
            v = umin64(v, red[t + 192]);
#pragma unroll
            for (int off = 32; off > 0; off >>= 1) {
                u64 o = __shfl_down(v, off);
                v = umin64(v, o);
            }
            if (t == 0) red[0] = v;
        }
        __syncthreads();
        int widx = (int)(red[0] & 0xffffffffu);
        if (t == 0) {
            idx_ws[row * KNB + it] = widx;
            out_idx[(long)row * KNB + it] = (float)widx;
            ds[widx] = 3.0e38f;
        }
        __syncthreads();
    }
}

// One block per row: features (bf16, LDS) -> MFMA (48x416)x(416x128) -> LN.
__global__ __launch_bounds__(256) void edge_mfma_kernel(
    const float* __restrict__ X, const int* __restrict__ ridx,
    const float* __restrict__ posW, const float* __restrict__ posb,
    const short8* __restrict__ Bp, const float* __restrict__ gamma,
    const float* __restrict__ beta, const int* __restrict__ idx_ws,
    float* __restrict__ outE) {
    __shared__ __align__(16) __hip_bfloat16 featbf[48 * FPAD];  // 42,240 B
    __shared__ float xi_s[15];
    __shared__ float xj_s[48][15];
    __shared__ float Dp[48][25];
    __shared__ int dclip[48];
    __shared__ float ps[48][4], ps2[48][4];
    __shared__ float mean_s[48], inv_s[48];

    float* accLDS = (float*)featbf;  // aliased AFTER mfma loop + barrier (24,960 B)

    const int row = blockIdx.x;
    const int b = row >> 11;
    const int t = threadIdx.x;

    if (t < 48) {
        int j = idx_ws[row * KNB + t];
        int off = ridx[row] - ridx[b * LSEQ + j] + 32;
        off = off < 0 ? 0 : (off > 64 ? 64 : off);
        dclip[t] = off;
        compute_token_atoms(X, (long)(b * LSEQ + j) * 42, xj_s[t]);
    } else if (t == 48) {
        compute_token_atoms(X, (long)row * 42, xi_s);
    }
    __syncthreads();

    for (int p = t; p < 48 * 25; p += 256) {
        int e = p / 25, pq = p % 25;
        int ai = pq / 5, aj = pq % 5;
        float dx = xi_s[ai * 3 + 0] - xj_s[e][aj * 3 + 0];
        float dy = xi_s[ai * 3 + 1] - xj_s[e][aj * 3 + 1];
        float dz = xi_s[ai * 3 + 2] - xj_s[e][aj * 3 + 2];
        Dp[e][pq] = sqrtf((dx * dx + dy * dy) + dz * dz + 1e-6f);
    }
    __syncthreads();

    // features: [16 pos | 400 rbf] per edge, bf16 into LDS
    const float inv_sigma = 0.8f;  // 1 / 1.25
#pragma unroll 1
    for (int e = 0; e < 48; ++e) {
        for (int f = t; f < 416; f += 256) {
            float v;
            if (f < 16) {
                v = posW[dclip[e] * 16 + f] + posb[f];
            } else {
                int p = (f - 16) >> 4, r = (f - 16) & 15;
                float mu = 2.0f + (20.0f / 15.0f) * (float)r;
                float x = (Dp[e][p] - mu) * inv_sigma;
                v = __expf(-x * x);
            }
            featbf[e * FPAD + f] = __float2bfloat16(v);
        }
    }
    __syncthreads();

    // MFMA: wave wv owns n-tiles {2wv, 2wv+1}; m-tiles 0..2 (48 edges)
    const int wv = t >> 6;
    const int l = t & 63;
    const int li = l & 15, lg = l >> 4;

    f32x4 acc[3][2];
#pragma unroll
    for (int m = 0; m < 3; ++m)
#pragma unroll
        for (int nn = 0; nn < 2; ++nn) acc[m][nn] = (f32x4){0.f, 0.f, 0.f, 0.f};

    const short8* featv = (const short8*)featbf;
#pragma unroll 1
    for (int s = 0; s < 13; ++s) {
        short8 afr[3];
#pragma unroll
        for (int m = 0; m < 3; ++m)
            afr[m] = featv[(m * 16 + li) * (FPAD / 8) + s * 4 + lg];
        short8 bfr[2];
#pragma unroll
        for (int nn = 0; nn < 2; ++nn)
            bfr[nn] = Bp[((wv * 2 + nn) * 13 + s) * 64 + l];
#pragma unroll
        for (int m = 0; m < 3; ++m)
#pragma unroll
            for (int nn = 0; nn < 2; ++nn)
                acc[m][nn] = __builtin_amdgcn_mfma_f32_16x16x32_bf16(
                    afr[m], bfr[nn], acc[m][nn], 0, 0, 0);
    }
    __syncthreads();  // featbf dead; safe to alias as accLDS

    // C/D layout: col = l&15, row = (l>>4)*4 + r  (m89-verified)
#pragma unroll
    for (int m = 0; m < 3; ++m)
#pragma unroll
        for (int nn = 0; nn < 2; ++nn)
#pragma unroll
            for (int r = 0; r < 4; ++r) {
                int e = m * 16 + lg * 4 + r;
                int c = (wv * 2 + nn) * 16 + li;
                accLDS[e * CPAD + c] = acc[m][nn][r];
            }
    __syncthreads();

    if (t < 192) {
        int e = t >> 2, q = t & 3;
        float s1 = 0.f, s2 = 0.f;
        for (int c = q * 32; c < q * 32 + 32; ++c) {
            float v = accLDS[e * CPAD + c];
            s1 += v;
            s2 = fmaf(v, v, s2);
        }
        ps[e][q] = s1;
        ps2[e][q] = s2;
    }
    __syncthreads();
    if (t < 48) {
        float S = (ps[t][0] + ps[t][1]) + (ps[t][2] + ps[t][3]);
        float S2 = (ps2[t][0] + ps2[t][1]) + (ps2[t][2] + ps2[t][3]);
        float m = S * (1.0f / 128.0f);
        float var = S2 * (1.0f / 128.0f) - m * m;
        mean_s[t] = m;
        inv_s[t] = rsqrtf(var + 1e-5f);
    }
    __syncthreads();

    const int c = t & 127;
    const float gm = gamma[c], bt = beta[c];
    const long base = (long)row * (KNB * 128);
    for (int idx = t; idx < KNB * 128; idx += 256) {
        int e = idx >> 7;
        float v = accLDS[e * CPAD + c];
        outE[base + idx] = (v - mean_s[e]) * inv_s[e] * gm + bt;
    }
}

extern "C" void kernel_launch(void* const* d_in, const int* in_sizes, int n_in,
                              void* d_out, int out_size, void* d_ws, size_t ws_size,
                              hipStream_t stream) {
    const float* X = (const float*)d_in[0];
    const float* Xm = (const float*)d_in[1];
    // d_in[2] = S : dead input (slot tables are token-independent)
    const int* ridx = (const int*)d_in[3];
    const float* posW = (const float*)d_in[4];
    const float* posb = (const float*)d_in[5];
    const float* edgeW = (const float*)d_in[6];
    const float* gamma = (const float*)d_in[7];
    const float* beta = (const float*)d_in[8];

    float* out = (float*)d_out;
    const long E_elems = (long)BATCH * LSEQ * KNB * 128;  // 25,165,824
    float* out_idx = out + E_elems;

    // ws layout: [0, 104 KiB) bf16 B-fragments; then int32 E_idx (786 KiB)
    short8* Bp = (short8*)d_ws;
    int* idx_ws = (int*)((char*)d_ws + 104 * 13 * 64 * 8 * 2 / 104 * 104);  // 106,496 B
    // (8 n-tiles * 13 k-steps * 64 lanes * 8 bf16 * 2 B = 106,496)

    pack_w_kernel<<<8 * 13, 64, 0, stream>>>(edgeW, Bp);
    topk_kernel<<<BATCH * LSEQ, 256, 0, stream>>>(X, Xm, idx_ws, out_idx);
    edge_mfma_kernel<<<BATCH * LSEQ, 256, 0, stream>>>(X, ridx, posW, posb, Bp,
                                                       gamma, beta, idx_ws, out);
}

// Round 4
// 237.287 us; speedup vs baseline: 2.7268x; 1.1839x over previous
//
#include <hip/hip_runtime.h>
#include <hip/hip_bf16.h>

#define LSEQ 2048
#define BATCH 2
#define KNB 48
#define FPAD 440   // feat row pad (bf16): 880B stride
#define CPAD 132   // acc row pad (f32): 528B stride, 16B-aligned

typedef unsigned long long u64;
typedef __attribute__((ext_vector_type(8))) short short8;
typedef __attribute__((ext_vector_type(4))) float f32x4;

__device__ __forceinline__ u64 umin64(u64 a, u64 b) { return a < b ? a : b; }
__device__ __forceinline__ u64 umax64(u64 a, u64 b) { return a > b ? a : b; }

// (a1,a2) := two smallest of {a1,a2,b1,b2}; inputs sorted pairs, keys distinct
__device__ __forceinline__ void merge2(u64& a1, u64& a2, u64 b1, u64 b2) {
    u64 lo = umin64(a1, b1);
    u64 hi = umax64(a1, b1);
    a2 = umin64(hi, umin64(a2, b2));
    a1 = lo;
}

// 5-atom X_all row (atoms 0..3 + virtual). base = float index of atom0.x
__device__ __forceinline__ void compute_token_atoms(const float* __restrict__ X,
                                                    long base, float* dst) {
    float a[12];
#pragma unroll
    for (int i = 0; i < 12; ++i) a[i] = X[base + i];
    // Xc = atom1, X1 = atom0, X2 = atom2  (VIRT_SLOTS = [1,0,2])
    float cx = a[3], cy = a[4], cz = a[5];
    float b1x = a[0] - cx, b1y = a[1] - cy, b1z = a[2] - cz;
    float b2x = a[6] - cx, b2y = a[7] - cy, b2z = a[8] - cz;
    float nx = b1y * b2z - b1z * b2y;
    float ny = b1z * b2x - b1x * b2z;
    float nz = b1x * b2y - b1y * b2x;
    const float WN = 0.58273431f, WB1 = -0.56802827f, WB2 = -0.54067466f;
#pragma unroll
    for (int i = 0; i < 12; ++i) dst[i] = a[i];
    dst[12] = WN * nx + WB1 * b1x + WB2 * b2x + cx;
    dst[13] = WN * ny + WB1 * b1y + WB2 * b2y + cy;
    dst[14] = WN * nz + WB1 * b1z + WB2 * b2z + cz;
}

// Pack edgeW into bf16 B-fragments (blocks 0..103) + Xc/mask float4 (104..167)
__global__ __launch_bounds__(64) void pack_kernel(const float* __restrict__ edgeW,
                                                  short8* __restrict__ Bp,
                                                  const float* __restrict__ X,
                                                  const float* __restrict__ Xm,
                                                  float4* __restrict__ Xc4) {
    int blk = blockIdx.x;
    int l = threadIdx.x;
    if (blk < 104) {
        int col = ((blk / 13) * 16) + (l & 15);
        int k0 = (blk % 13) * 32 + (l >> 4) * 8;
        union { short8 v; __hip_bfloat16 h[8]; } u;
#pragma unroll
        for (int j = 0; j < 8; ++j)
            u.h[j] = __float2bfloat16(edgeW[(k0 + j) * 128 + col]);
        Bp[(long)blk * 64 + l] = u.v;
    } else {
        int i = (blk - 104) * 64 + l;  // 0..4095
        long base = (long)i * 42 + 3;  // atom 1
        float4 p;
        p.x = X[base];
        p.y = X[base + 1];
        p.z = X[base + 2];
        p.w = Xm[(long)i * 14 + 1];
        Xc4[i] = p;
    }
}

// One block per row: top-48 select -> features -> MFMA -> LayerNorm -> store.
__global__ __launch_bounds__(256) void fused_kernel(
    const float* __restrict__ X, const int* __restrict__ ridx,
    const float* __restrict__ posW, const float* __restrict__ posb,
    const short8* __restrict__ Bp, const float* __restrict__ gamma,
    const float* __restrict__ beta, const float4* __restrict__ Xc4,
    float* __restrict__ outE, float* __restrict__ out_idx) {
    __shared__ __align__(16) __hip_bfloat16 featbf[48 * FPAD];  // 42,240 B
    __shared__ float xi_s[15];
    __shared__ float xj_s[48][15];
    __shared__ int dclip[48];
    __shared__ int idx_sh[KNB];
    __shared__ u64 wpair[2][8];
    __shared__ float ps[48][4], ps2[48][4];
    __shared__ float mean_s[48], inv_s[48];

    float* accLDS = (float*)featbf;  // aliased after MFMA + barrier

    const int row = blockIdx.x;
    const int b = row >> 11;
    const int t = threadIdx.x;
    const int wv = t >> 6;
    const int lane = t & 63;
    const int b0 = b << 11;

    // ---- Phase A: top-48 selection, keys in registers ----
    {
        float4 pi = Xc4[row];
        const float xi0 = pi.x, xi1 = pi.y, xi2 = pi.z, mi = pi.w;
        u64 K0, K1, K2, K3, K4, K5, K6, K7;
#define MAKEKEY(kk, KV)                                                        \
    {                                                                          \
        int j = t + kk * 256;                                                  \
        float4 pj = Xc4[b0 + j];                                               \
        float dx = xi0 - pj.x, dy = xi1 - pj.y, dz = xi2 - pj.z;               \
        float d2 = __fadd_rn(__fadd_rn(__fmul_rn(dx, dx), __fmul_rn(dy, dy)), \
                             __fmul_rn(dz, dz));                               \
        float D = sqrtf(__fadd_rn(d2, 1e-6f));                                 \
        float da = D + (1.0f - mi * pj.w) * 1000000.0f;                        \
        KV = ((u64)__float_as_uint(da) << 32) | (unsigned)j;                   \
    }
        MAKEKEY(0, K0) MAKEKEY(1, K1) MAKEKEY(2, K2) MAKEKEY(3, K3)
        MAKEKEY(4, K4) MAKEKEY(5, K5) MAKEKEY(6, K6) MAKEKEY(7, K7)
#undef MAKEKEY

#pragma unroll 1
        for (int r = 0; r < KNB / 2; ++r) {
            // local top-2 of 8 keys
            u64 a1 = umin64(K0, K1), a2 = umax64(K0, K1);
            u64 c1 = umin64(K2, K3), c2 = umax64(K2, K3);
            u64 d1 = umin64(K4, K5), d2 = umax64(K4, K5);
            u64 e1 = umin64(K6, K7), e2 = umax64(K6, K7);
            merge2(a1, a2, c1, c2);
            merge2(d1, d2, e1, e2);
            merge2(a1, a2, d1, d2);
            // wave butterfly (disjoint lane-sets each step; keys distinct)
#pragma unroll
            for (int off = 1; off < 64; off <<= 1) {
                u64 o1 = __shfl_xor(a1, off, 64);
                u64 o2 = __shfl_xor(a2, off, 64);
                merge2(a1, a2, o1, o2);
            }
            int pr = r & 1;
            if (lane == 0) {
                wpair[pr][wv * 2] = a1;
                wpair[pr][wv * 2 + 1] = a2;
            }
            __syncthreads();
            u64 g1 = wpair[pr][0], g2 = wpair[pr][1];
            merge2(g1, g2, wpair[pr][2], wpair[pr][3]);
            merge2(g1, g2, wpair[pr][4], wpair[pr][5]);
            merge2(g1, g2, wpair[pr][6], wpair[pr][7]);
            int i0 = 2 * r;
            if (t == i0) {
                int wi = (int)(g1 & 0xffffffffu);
                idx_sh[i0] = wi;
                out_idx[(long)row * KNB + i0] = (float)wi;
            }
            if (t == i0 + 1) {
                int wi = (int)(g2 & 0xffffffffu);
                idx_sh[i0 + 1] = wi;
                out_idx[(long)row * KNB + i0 + 1] = (float)wi;
            }
            // kill extracted keys (only the owner threads match)
            if (K0 == g1 || K0 == g2) K0 = ~0ULL;
            if (K1 == g1 || K1 == g2) K1 = ~0ULL;
            if (K2 == g1 || K2 == g2) K2 = ~0ULL;
            if (K3 == g1 || K3 == g2) K3 = ~0ULL;
            if (K4 == g1 || K4 == g2) K4 = ~0ULL;
            if (K5 == g1 || K5 == g2) K5 = ~0ULL;
            if (K6 == g1 || K6 == g2) K6 = ~0ULL;
            if (K7 == g1 || K7 == g2) K7 = ~0ULL;
        }
    }
    __syncthreads();  // idx_sh ready

    // ---- Phase B: gather neighbor atoms ----
    if (t < 48) {
        int j = idx_sh[t];
        int off = ridx[row] - ridx[b0 + j] + 32;
        off = off < 0 ? 0 : (off > 64 ? 64 : off);
        dclip[t] = off;
        compute_token_atoms(X, (long)(b0 + j) * 42, xj_s[t]);
    } else if (t == 48) {
        compute_token_atoms(X, (long)row * 42, xi_s);
    }
    __syncthreads();

    // pos features: f 0..15
    for (int s5 = t; s5 < 48 * 16; s5 += 256) {
        int e = s5 >> 4, f = s5 & 15;
        featbf[e * FPAD + f] = __float2bfloat16(posW[dclip[e] * 16 + f] + posb[f]);
    }
    // RBF features: per (e, pq) compute D once, 16 RBFs, packed 32B write
#pragma unroll 1
    for (int s5 = t; s5 < 48 * 25; s5 += 256) {
        int e = s5 / 25, pq = s5 - e * 25;
        int ai = pq / 5, aj = pq - ai * 5;
        float dx = xi_s[ai * 3 + 0] - xj_s[e][aj * 3 + 0];
        float dy = xi_s[ai * 3 + 1] - xj_s[e][aj * 3 + 1];
        float dz = xi_s[ai * 3 + 2] - xj_s[e][aj * 3 + 2];
        float D = sqrtf((dx * dx + dy * dy) + dz * dz + 1e-6f);
        float x0 = (D - 2.0f) * 0.8f;
        union { short8 v[2]; __hip_bfloat16 h[16]; } u;
#pragma unroll
        for (int rr = 0; rr < 16; ++rr) {
            float x = x0 - 1.0666667f * (float)rr;
            u.h[rr] = __float2bfloat16(__expf(-x * x));
        }
        short8* dst = (short8*)&featbf[e * FPAD + 16 + pq * 16];
        dst[0] = u.v[0];
        dst[1] = u.v[1];
    }
    __syncthreads();

    // ---- MFMA: (48 x 416) x (416 x 128) ----
    const int li = lane & 15, lg = lane >> 4;
    f32x4 acc[3][2];
#pragma unroll
    for (int m = 0; m < 3; ++m)
#pragma unroll
        for (int nn = 0; nn < 2; ++nn) acc[m][nn] = (f32x4){0.f, 0.f, 0.f, 0.f};

    const short8* featv = (const short8*)featbf;
#pragma unroll 1
    for (int s = 0; s < 13; ++s) {
        short8 afr[3];
#pragma unroll
        for (int m = 0; m < 3; ++m)
            afr[m] = featv[(m * 16 + li) * (FPAD / 8) + s * 4 + lg];
        short8 bfr[2];
#pragma unroll
        for (int nn = 0; nn < 2; ++nn)
            bfr[nn] = Bp[((wv * 2 + nn) * 13 + s) * 64 + lane];
#pragma unroll
        for (int m = 0; m < 3; ++m)
#pragma unroll
            for (int nn = 0; nn < 2; ++nn)
                acc[m][nn] = __builtin_amdgcn_mfma_f32_16x16x32_bf16(
                    afr[m], bfr[nn], acc[m][nn], 0, 0, 0);
    }
    __syncthreads();  // featbf dead; alias as accLDS

    // C/D layout: col = lane&15, row = (lane>>4)*4 + r
#pragma unroll
    for (int m = 0; m < 3; ++m)
#pragma unroll
        for (int nn = 0; nn < 2; ++nn)
#pragma unroll
            for (int r = 0; r < 4; ++r) {
                int e = m * 16 + lg * 4 + r;
                int c = (wv * 2 + nn) * 16 + li;
                accLDS[e * CPAD + c] = acc[m][nn][r];
            }
    __syncthreads();

    // LayerNorm partials (vectorized)
    if (t < 192) {
        int e = t >> 2, q = t & 3;
        const f32x4* rp = (const f32x4*)&accLDS[e * CPAD + q * 32];
        float s1 = 0.f, s2 = 0.f;
#pragma unroll
        for (int i = 0; i < 8; ++i) {
            f32x4 v = rp[i];
#pragma unroll
            for (int j = 0; j < 4; ++j) {
                s1 += v[j];
                s2 = fmaf(v[j], v[j], s2);
            }
        }
        ps[e][q] = s1;
        ps2[e][q] = s2;
    }
    __syncthreads();
    if (t < 48) {
        float S = (ps[t][0] + ps[t][1]) + (ps[t][2] + ps[t][3]);
        float S2 = (ps2[t][0] + ps2[t][1]) + (ps2[t][2] + ps2[t][3]);
        float m = S * (1.0f / 128.0f);
        float var = S2 * (1.0f / 128.0f) - m * m;
        mean_s[t] = m;
        inv_s[t] = rsqrtf(var + 1e-5f);
    }
    __syncthreads();

    // normalize + store, float4
    const int cg = (t & 31) * 4;
    const float4 gm4 = *(const float4*)&gamma[cg];
    const float4 bt4 = *(const float4*)&beta[cg];
    const long base = (long)row * (KNB * 128);
    for (int s5 = t; s5 < 48 * 32; s5 += 256) {
        int e = s5 >> 5;
        f32x4 v = *(const f32x4*)&accLDS[e * CPAD + cg];
        float mn = mean_s[e], iv = inv_s[e];
        float4 o;
        o.x = (v[0] - mn) * iv * gm4.x + bt4.x;
        o.y = (v[1] - mn) * iv * gm4.y + bt4.y;
        o.z = (v[2] - mn) * iv * gm4.z + bt4.z;
        o.w = (v[3] - mn) * iv * gm4.w + bt4.w;
        *(float4*)&outE[base + e * 128 + cg] = o;
    }
}

extern "C" void kernel_launch(void* const* d_in, const int* in_sizes, int n_in,
                              void* d_out, int out_size, void* d_ws, size_t ws_size,
                              hipStream_t stream) {
    const float* X = (const float*)d_in[0];
    const float* Xm = (const float*)d_in[1];
    // d_in[2] = S : dead input (slot tables are token-independent)
    const int* ridx = (const int*)d_in[3];
    const float* posW = (const float*)d_in[4];
    const float* posb = (const float*)d_in[5];
    const float* edgeW = (const float*)d_in[6];
    const float* gamma = (const float*)d_in[7];
    const float* beta = (const float*)d_in[8];

    float* out = (float*)d_out;
    const long E_elems = (long)BATCH * LSEQ * KNB * 128;  // 25,165,824
    float* out_idx = out + E_elems;

    // ws: [0, 106496) Bp bf16 B-fragments; [106496, +64KiB) Xc4 float4
    short8* Bp = (short8*)d_ws;
    float4* Xc4 = (float4*)((char*)d_ws + 106496);

    pack_kernel<<<168, 64, 0, stream>>>(edgeW, Bp, X, Xm, Xc4);
    fused_kernel<<<BATCH * LSEQ, 256, 0, stream>>>(X, ridx, posW, posb, Bp, gamma,
                                                   beta, Xc4, out, out_idx);
}

// Round 5
// 116.050 us; speedup vs baseline: 5.5756x; 2.0447x over previous
//
#include <hip/hip_runtime.h>
#include <hip/hip_bf16.h>

#define LSEQ 2048
#define BATCH 2
#define KNB 48
#define FPAD 440   // feat row pad (bf16): 880B stride -> 2-way LDS conflict (free)
#define CPAD 132   // acc row pad (f32)

typedef unsigned long long u64;
typedef __attribute__((ext_vector_type(8))) short short8;
typedef __attribute__((ext_vector_type(4))) float f32x4;

__device__ __forceinline__ u64 umin64(u64 a, u64 b) { return a < b ? a : b; }
__device__ __forceinline__ u64 umax64(u64 a, u64 b) { return a > b ? a : b; }

// Ascending bitonic sort of 64 u64 keys across one wave (lane-indexed).
__device__ __forceinline__ u64 bitonic64(u64 key, int lane) {
#pragma unroll
    for (int k = 2; k <= 64; k <<= 1) {
#pragma unroll
        for (int j = k >> 1; j > 0; j >>= 1) {
            u64 p = __shfl_xor(key, j, 64);
            u64 mn = umin64(key, p), mx = umax64(key, p);
            bool up = (lane & k) == 0;
            bool lower = (lane & j) == 0;
            key = (lower == up) ? mn : mx;
        }
    }
    return key;
}

// wave-0 helper: find first bin with cum >= K over 256-bin hist; out={bin, below}
__device__ __forceinline__ void scan_find(const int* hist, int K, int* out,
                                          int lane) {
    int bb = lane * 4;
    int c0 = hist[bb], c1 = hist[bb + 1], c2 = hist[bb + 2], c3 = hist[bb + 3];
    int s = c0 + c1 + c2 + c3;
    int inc = s;
#pragma unroll
    for (int off = 1; off < 64; off <<= 1) {
        int o = __shfl_up(inc, off, 64);
        if (lane >= off) inc += o;
    }
    int prev = inc - s;
    int cc[4] = {c0, c1, c2, c3};
#pragma unroll
    for (int j2 = 0; j2 < 4; ++j2) {
        int cum = prev + cc[j2];
        if (prev < K && cum >= K) {
            out[0] = bb + j2;
            out[1] = prev;
        }
        prev = cum;
    }
}

// Pack edgeW into bf16 B-fragments (blocks 0..103) + Xc/mask float4 (104..167)
__global__ __launch_bounds__(64) void pack_kernel(const float* __restrict__ edgeW,
                                                  short8* __restrict__ Bp,
                                                  const float* __restrict__ X,
                                                  const float* __restrict__ Xm,
                                                  float4* __restrict__ Xc4) {
    int blk = blockIdx.x;
    int l = threadIdx.x;
    if (blk < 104) {
        int col = ((blk / 13) * 16) + (l & 15);
        int k0 = (blk % 13) * 32 + (l >> 4) * 8;
        union { short8 v; __hip_bfloat16 h[8]; } u;
#pragma unroll
        for (int j = 0; j < 8; ++j)
            u.h[j] = __float2bfloat16(edgeW[(k0 + j) * 128 + col]);
        Bp[(long)blk * 64 + l] = u.v;
    } else {
        int i = (blk - 104) * 64 + l;  // 0..4095
        long base = (long)i * 42 + 3;  // atom 1
        float4 p;
        p.x = X[base];
        p.y = X[base + 1];
        p.z = X[base + 2];
        p.w = Xm[(long)i * 14 + 1];
        Xc4[i] = p;
    }
}

// One block per row: radix-select top-48 -> features -> MFMA -> LN -> store.
__global__ __launch_bounds__(256) void fused_kernel(
    const float* __restrict__ X, const int* __restrict__ ridx,
    const float* __restrict__ posW, const float* __restrict__ posb,
    const short8* __restrict__ Bp, const float* __restrict__ gamma,
    const float* __restrict__ beta, const float4* __restrict__ Xc4,
    float* __restrict__ outE, float* __restrict__ out_idx) {
    __shared__ __align__(16) __hip_bfloat16 featbf[48 * FPAD];  // 42,240 B
    __shared__ float xi_s[15];
    __shared__ float xj_s[48][15];
    __shared__ int dclip[48];
    __shared__ int idx_sh[KNB];
    __shared__ int hist[256];
    __shared__ u64 selA[64];
    __shared__ u64 candA[64];
    __shared__ int cnts[2];
    __shared__ int scanres[2];
    __shared__ float ps[48][4], ps2[48][4];
    __shared__ float mean_s[48], inv_s[48];

    float* accLDS = (float*)featbf;  // aliased after MFMA + barrier

    const int row = blockIdx.x;
    const int b = row >> 11;
    const int t = threadIdx.x;
    const int wv = t >> 6;
    const int lane = t & 63;
    const int b0 = b << 11;

    // ---- Phase A: top-48 via 2-pass radix select on u64 keys ----
    {
        float4 pi = Xc4[row];
        const float xi0 = pi.x, xi1 = pi.y, xi2 = pi.z, mi = pi.w;
        u64 K[8];
#pragma unroll
        for (int kk = 0; kk < 8; ++kk) {
            int j = t + kk * 256;
            float4 pj = Xc4[b0 + j];
            float dx = xi0 - pj.x, dy = xi1 - pj.y, dz = xi2 - pj.z;
            // match numpy exactly: ((dx^2+dy^2)+dz^2)+1e-6, no fma contraction
            float d2 = __fadd_rn(__fadd_rn(__fmul_rn(dx, dx), __fmul_rn(dy, dy)),
                                 __fmul_rn(dz, dz));
            float D = sqrtf(__fadd_rn(d2, 1e-6f));
            float da = D + (1.0f - mi * pj.w) * 1000000.0f;
            K[kk] = ((u64)__float_as_uint(da) << 32) | (unsigned)j;
        }

        hist[t] = 0;
        __syncthreads();
#pragma unroll
        for (int kk = 0; kk < 8; ++kk)
            atomicAdd(&hist[(int)(K[kk] >> 56)], 1);
        __syncthreads();
        if (wv == 0) scan_find(hist, KNB, scanres, lane);
        __syncthreads();
        const int B1 = scanres[0];
        const int need1 = KNB - scanres[1];
        __syncthreads();
        hist[t] = 0;
        if (t == 0) { cnts[0] = 0; cnts[1] = 0; }
        __syncthreads();
#pragma unroll
        for (int kk = 0; kk < 8; ++kk)
            if ((int)(K[kk] >> 56) == B1)
                atomicAdd(&hist[(int)((K[kk] >> 48) & 0xFF)], 1);
        __syncthreads();
        if (wv == 0) scan_find(hist, need1, scanres, lane);
        __syncthreads();
        const unsigned T16 = ((unsigned)B1 << 8) | (unsigned)scanres[0];
        const int selbase = (KNB - need1) + scanres[1];
        const int need2 = KNB - selbase;
#pragma unroll
        for (int kk = 0; kk < 8; ++kk) {
            unsigned k16 = (unsigned)(K[kk] >> 48);
            if (k16 < T16) {
                int p = atomicAdd(&cnts[0], 1);
                selA[p] = K[kk];
            } else if (k16 == T16) {
                int p = atomicAdd(&cnts[1], 1);
                if (p < 64) candA[p] = K[kk];
            }
        }
        __syncthreads();
        const int candcnt = cnts[1];
        if (wv == 0) {
            if (candcnt <= 64) {
                u64 kk = (lane < candcnt) ? candA[lane] : ~0ULL;
                kk = bitonic64(kk, lane);
                if (lane < need2) selA[selbase + lane] = kk;
            } else {
                // exact fallback (expected never for this data)
                for (int r = 0; r < need2; ++r) {
                    u64 best = ~0ULL;
                    for (int q = lane; q < candcnt && q < 64; q += 64)
                        best = umin64(best, candA[q]);
#pragma unroll
                    for (int off = 32; off > 0; off >>= 1)
                        best = umin64(best, __shfl_xor(best, off, 64));
                    if (lane == 0) selA[selbase + r] = best;
                    for (int q = lane; q < candcnt && q < 64; q += 64)
                        if (candA[q] == best) candA[q] = ~0ULL;
                }
            }
        }
        __syncthreads();
        if (wv == 0) {
            u64 kk = (lane < KNB) ? selA[lane] : ~0ULL;
            kk = bitonic64(kk, lane);
            if (lane < KNB) {
                int wi = (int)(kk & 0xffffffffu);
                idx_sh[lane] = wi;
                out_idx[(long)row * KNB + lane] = (float)wi;
            }
        }
    }
    __syncthreads();  // idx_sh ready

    // ---- Phase B: parallel neighbor-atom gather ----
    if (t < 192) {
        int e = t >> 2, a = t & 3;
        int j = idx_sh[e];
        long bb = (long)(b0 + j) * 42 + a * 3;
        float* d = &xj_s[e][a * 3];
        d[0] = X[bb];
        d[1] = X[bb + 1];
        d[2] = X[bb + 2];
    } else if (t < 196) {
        int a = t - 192;
        long bb = (long)row * 42 + a * 3;
        xi_s[a * 3 + 0] = X[bb];
        xi_s[a * 3 + 1] = X[bb + 1];
        xi_s[a * 3 + 2] = X[bb + 2];
    }
    if (t < 48) {
        int j = idx_sh[t];
        int off = ridx[row] - ridx[b0 + j] + 32;
        dclip[t] = off < 0 ? 0 : (off > 64 ? 64 : off);
    }
    __syncthreads();
    // virtual atom from LDS (Xc=atom1, X1=atom0, X2=atom2)
    if (t < 49) {
        float* d = (t < 48) ? xj_s[t] : xi_s;
        float cx = d[3], cy = d[4], cz = d[5];
        float b1x = d[0] - cx, b1y = d[1] - cy, b1z = d[2] - cz;
        float b2x = d[6] - cx, b2y = d[7] - cy, b2z = d[8] - cz;
        float nx = b1y * b2z - b1z * b2y;
        float ny = b1z * b2x - b1x * b2z;
        float nz = b1x * b2y - b1y * b2x;
        const float WN = 0.58273431f, WB1 = -0.56802827f, WB2 = -0.54067466f;
        d[12] = WN * nx + WB1 * b1x + WB2 * b2x + cx;
        d[13] = WN * ny + WB1 * b1y + WB2 * b2y + cy;
        d[14] = WN * nz + WB1 * b1z + WB2 * b2z + cz;
    }
    __syncthreads();

    // pos features: f 0..15
    for (int s5 = t; s5 < 48 * 16; s5 += 256) {
        int e = s5 >> 4, f = s5 & 15;
        featbf[e * FPAD + f] = __float2bfloat16(posW[dclip[e] * 16 + f] + posb[f]);
    }
    // RBF features: per (e, pq) compute D once, 16 RBFs, two 16B LDS writes
#pragma unroll 1
    for (int s5 = t; s5 < 48 * 25; s5 += 256) {
        int e = s5 / 25, pq = s5 - e * 25;
        int ai = pq / 5, aj = pq - ai * 5;
        float dx = xi_s[ai * 3 + 0] - xj_s[e][aj * 3 + 0];
        float dy = xi_s[ai * 3 + 1] - xj_s[e][aj * 3 + 1];
        float dz = xi_s[ai * 3 + 2] - xj_s[e][aj * 3 + 2];
        float D = sqrtf((dx * dx + dy * dy) + dz * dz + 1e-6f);
        float x0 = (D - 2.0f) * 0.8f;
        union { short8 v[2]; __hip_bfloat16 h[16]; } u;
#pragma unroll
        for (int rr = 0; rr < 16; ++rr) {
            float x = x0 - 1.0666667f * (float)rr;
            u.h[rr] = __float2bfloat16(__expf(-x * x));
        }
        short8* dst = (short8*)&featbf[e * FPAD + 16 + pq * 16];
        dst[0] = u.v[0];
        dst[1] = u.v[1];
    }
    __syncthreads();

    // ---- MFMA: (48 x 416) x (416 x 128) ----
    const int li = lane & 15, lg = lane >> 4;
    f32x4 acc[3][2];
#pragma unroll
    for (int m = 0; m < 3; ++m)
#pragma unroll
        for (int nn = 0; nn < 2; ++nn) acc[m][nn] = (f32x4){0.f, 0.f, 0.f, 0.f};

    const short8* featv = (const short8*)featbf;
#pragma unroll 1
    for (int s = 0; s < 13; ++s) {
        short8 afr[3];
#pragma unroll
        for (int m = 0; m < 3; ++m)
            afr[m] = featv[(m * 16 + li) * (FPAD / 8) + s * 4 + lg];
        short8 bfr[2];
#pragma unroll
        for (int nn = 0; nn < 2; ++nn)
            bfr[nn] = Bp[((wv * 2 + nn) * 13 + s) * 64 + lane];
#pragma unroll
        for (int m = 0; m < 3; ++m)
#pragma unroll
            for (int nn = 0; nn < 2; ++nn)
                acc[m][nn] = __builtin_amdgcn_mfma_f32_16x16x32_bf16(
                    afr[m], bfr[nn], acc[m][nn], 0, 0, 0);
    }
    __syncthreads();  // featbf dead; alias as accLDS

    // C/D layout: col = lane&15, row = (lane>>4)*4 + r
#pragma unroll
    for (int m = 0; m < 3; ++m)
#pragma unroll
        for (int nn = 0; nn < 2; ++nn)
#pragma unroll
            for (int r = 0; r < 4; ++r) {
                int e = m * 16 + lg * 4 + r;
                int c = (wv * 2 + nn) * 16 + li;
                accLDS[e * CPAD + c] = acc[m][nn][r];
            }
    __syncthreads();

    // LayerNorm partials (vectorized)
    if (t < 192) {
        int e = t >> 2, q = t & 3;
        const f32x4* rp = (const f32x4*)&accLDS[e * CPAD + q * 32];
        float s1 = 0.f, s2 = 0.f;
#pragma unroll
        for (int i = 0; i < 8; ++i) {
            f32x4 v = rp[i];
#pragma unroll
            for (int j = 0; j < 4; ++j) {
                s1 += v[j];
                s2 = fmaf(v[j], v[j], s2);
            }
        }
        ps[e][q] = s1;
        ps2[e][q] = s2;
    }
    __syncthreads();
    if (t < 48) {
        float S = (ps[t][0] + ps[t][1]) + (ps[t][2] + ps[t][3]);
        float S2 = (ps2[t][0] + ps2[t][1]) + (ps2[t][2] + ps2[t][3]);
        float m = S * (1.0f / 128.0f);
        float var = S2 * (1.0f / 128.0f) - m * m;
        mean_s[t] = m;
        inv_s[t] = rsqrtf(var + 1e-5f);
    }
    __syncthreads();

    // normalize + store, float4
    const int cg = (t & 31) * 4;
    const float4 gm4 = *(const float4*)&gamma[cg];
    const float4 bt4 = *(const float4*)&beta[cg];
    const long base = (long)row * (KNB * 128);
    for (int s5 = t; s5 < 48 * 32; s5 += 256) {
        int e = s5 >> 5;
        f32x4 v = *(const f32x4*)&accLDS[e * CPAD + cg];
        float mn = mean_s[e], iv = inv_s[e];
        float4 o;
        o.x = (v[0] - mn) * iv * gm4.x + bt4.x;
        o.y = (v[1] - mn) * iv * gm4.y + bt4.y;
        o.z = (v[2] - mn) * iv * gm4.z + bt4.z;
        o.w = (v[3] - mn) * iv * gm4.w + bt4.w;
        *(float4*)&outE[base + e * 128 + cg] = o;
    }
}

extern "C" void kernel_launch(void* const* d_in, const int* in_sizes, int n_in,
                              void* d_out, int out_size, void* d_ws, size_t ws_size,
                              hipStream_t stream) {
    const float* X = (const float*)d_in[0];
    const float* Xm = (const float*)d_in[1];
    // d_in[2] = S : dead input (slot tables are token-independent)
    const int* ridx = (const int*)d_in[3];
    const float* posW = (const float*)d_in[4];
    const float* posb = (const float*)d_in[5];
    const float* edgeW = (const float*)d_in[6];
    const float* gamma = (const float*)d_in[7];
    const float* beta = (const float*)d_in[8];

    float* out = (float*)d_out;
    const long E_elems = (long)BATCH * LSEQ * KNB * 128;  // 25,165,824
    float* out_idx = out + E_elems;

    // ws: [0, 106496) Bp bf16 B-fragments; [106496, +64KiB) Xc4 float4
    short8* Bp = (short8*)d_ws;
    float4* Xc4 = (float4*)((char*)d_ws + 106496);

    pack_kernel<<<168, 64, 0, stream>>>(edgeW, Bp, X, Xm, Xc4);
    fused_kernel<<<BATCH * LSEQ, 256, 0, stream>>>(X, ridx, posW, posb, Bp, gamma,
                                                   beta, Xc4, out, out_idx);
}

// Round 6
// 95.637 us; speedup vs baseline: 6.7656x; 1.2134x over previous
//
#include <hip/hip_runtime.h>
#include <hip/hip_bf16.h>

#define LSEQ 2048
#define BATCH 2
#define KNB 48
#define FPAD 440   // feat row pad (bf16): 880B stride
#define CPAD 132   // acc row pad (f32)

typedef unsigned long long u64;
typedef __attribute__((ext_vector_type(8))) short short8;
typedef __attribute__((ext_vector_type(4))) float f32x4;

// wave-0 helper: find first bin with cum >= K over 256-bin hist; out={bin, below}
__device__ __forceinline__ void scan_find(const int* hist, int K, int* out,
                                          int lane) {
    int bb = lane * 4;
    int c0 = hist[bb], c1 = hist[bb + 1], c2 = hist[bb + 2], c3 = hist[bb + 3];
    int s = c0 + c1 + c2 + c3;
    int inc = s;
#pragma unroll
    for (int off = 1; off < 64; off <<= 1) {
        int o = __shfl_up(inc, off, 64);
        if (lane >= off) inc += o;
    }
    int prev = inc - s;
    int cc[4] = {c0, c1, c2, c3};
#pragma unroll
    for (int j2 = 0; j2 < 4; ++j2) {
        int cum = prev + cc[j2];
        if (prev < K && cum >= K) {
            out[0] = bb + j2;
            out[1] = prev;
        }
        prev = cum;
    }
}

// Pack edgeW into bf16 B-fragments (blocks 0..103) + Xc/mask float4 (104..167)
__global__ __launch_bounds__(64) void pack_kernel(const float* __restrict__ edgeW,
                                                  short8* __restrict__ Bp,
                                                  const float* __restrict__ X,
                                                  const float* __restrict__ Xm,
                                                  float4* __restrict__ Xc4) {
    int blk = blockIdx.x;
    int l = threadIdx.x;
    if (blk < 104) {
        int col = ((blk / 13) * 16) + (l & 15);
        int k0 = (blk % 13) * 32 + (l >> 4) * 8;
        union { short8 v; __hip_bfloat16 h[8]; } u;
#pragma unroll
        for (int j = 0; j < 8; ++j)
            u.h[j] = __float2bfloat16(edgeW[(k0 + j) * 128 + col]);
        Bp[(long)blk * 64 + l] = u.v;
    } else {
        int i = (blk - 104) * 64 + l;  // 0..4095
        long base = (long)i * 42 + 3;  // atom 1
        float4 p;
        p.x = X[base];
        p.y = X[base + 1];
        p.z = X[base + 2];
        p.w = Xm[(long)i * 14 + 1];
        Xc4[i] = p;
    }
}

// One block per row: radix-select top-48 -> features -> MFMA -> LN -> store.
__global__ __launch_bounds__(256, 3) void fused_kernel(
    const float* __restrict__ X, const int* __restrict__ ridx,
    const float* __restrict__ posW, const float* __restrict__ posb,
    const short8* __restrict__ Bp, const float* __restrict__ gamma,
    const float* __restrict__ beta, const float4* __restrict__ Xc4,
    float* __restrict__ outE, float* __restrict__ out_idx) {
    __shared__ __align__(16) __hip_bfloat16 featbf[48 * FPAD];  // 42,240 B
    __shared__ float xi_s[15];
    __shared__ float xj_s[48][15];
    __shared__ int dclip[48];
    __shared__ int idx_sh[KNB];
    __shared__ int hist1[256], hist2[256];
    __shared__ u64 selA[64];
    __shared__ u64 candA[64];
    __shared__ int cnts[2];
    __shared__ int scanA[2], scanB[2];
    __shared__ float ps[48][4], ps2[48][4];
    __shared__ float mean_s[48], inv_s[48];

    float* accLDS = (float*)featbf;  // aliased after MFMA + barrier

    const int row = blockIdx.x;
    const int b = row >> 11;
    const int t = threadIdx.x;
    const int wv = t >> 6;
    const int lane = t & 63;
    const int b0 = b << 11;

    // ---- Phase A: top-48 via 2-pass radix select on u64 keys ----
    u64 K[8];
    {
        float4 pjv[8];
#pragma unroll
        for (int kk = 0; kk < 8; ++kk) pjv[kk] = Xc4[b0 + t + kk * 256];
        float4 pi = Xc4[row];
        const float xi0 = pi.x, xi1 = pi.y, xi2 = pi.z, mi = pi.w;
#pragma unroll
        for (int kk = 0; kk < 8; ++kk) {
            int j = t + kk * 256;
            float dx = xi0 - pjv[kk].x, dy = xi1 - pjv[kk].y, dz = xi2 - pjv[kk].z;
            // match numpy exactly: ((dx^2+dy^2)+dz^2)+1e-6, no fma contraction
            float d2 = __fadd_rn(__fadd_rn(__fmul_rn(dx, dx), __fmul_rn(dy, dy)),
                                 __fmul_rn(dz, dz));
            float D = sqrtf(__fadd_rn(d2, 1e-6f));
            float da = D + (1.0f - mi * pjv[kk].w) * 1000000.0f;
            K[kk] = ((u64)__float_as_uint(da) << 32) | (unsigned)j;
        }
    }

    // prefetch ALL B-fragments for this wave into registers (landed by MFMA)
    short8 bfrAll[26];
    {
        const short8* bp = Bp + (long)(wv * 26) * 64 + lane;
#pragma unroll
        for (int q = 0; q < 26; ++q) bfrAll[q] = bp[q * 64];
    }

    hist1[t] = 0;
    hist2[t] = 0;
    if (t == 0) { cnts[0] = 0; cnts[1] = 0; }
    __syncthreads();
#pragma unroll
    for (int kk = 0; kk < 8; ++kk) atomicAdd(&hist1[(int)(K[kk] >> 56)], 1);
    __syncthreads();
    if (wv == 0) scan_find(hist1, KNB, scanA, lane);
    __syncthreads();
    const int B1 = scanA[0];
    const int need1 = KNB - scanA[1];
#pragma unroll
    for (int kk = 0; kk < 8; ++kk)
        if ((int)(K[kk] >> 56) == B1)
            atomicAdd(&hist2[(int)((K[kk] >> 48) & 0xFF)], 1);
    __syncthreads();
    if (wv == 0) scan_find(hist2, need1, scanB, lane);
    __syncthreads();
    const unsigned T16 = ((unsigned)B1 << 8) | (unsigned)scanB[0];
    const int selbase = (KNB - need1) + scanB[1];
    const int need2 = KNB - selbase;
#pragma unroll
    for (int kk = 0; kk < 8; ++kk) {
        unsigned k16 = (unsigned)(K[kk] >> 48);
        if (k16 < T16) {
            int p = atomicAdd(&cnts[0], 1);
            selA[p] = K[kk];
        } else if (k16 == T16) {
            int p = atomicAdd(&cnts[1], 1);
            if (p < 64) candA[p] = K[kk];
        }
    }
    __syncthreads();
    {
        int candcnt = cnts[1] < 64 ? cnts[1] : 64;
        if (t < 64) {
            bool valid = t < candcnt;
            u64 key = valid ? candA[t] : ~0ULL;
            int rank = 0;
            for (int j = 0; j < candcnt; ++j) rank += (candA[j] < key);
            if (valid && rank < need2) selA[selbase + rank] = key;
        }
    }
    __syncthreads();
    if (t < KNB) {
        u64 key = selA[t];
        int rank = 0;
#pragma unroll
        for (int j = 0; j < KNB; ++j) rank += (selA[j] < key);
        int wi = (int)(key & 0xffffffffu);
        idx_sh[rank] = wi;
        out_idx[(long)row * KNB + rank] = (float)wi;
    }
    __syncthreads();  // idx_sh ready

    // ---- Phase B: parallel neighbor-atom gather ----
    if (t < 192) {
        int e = t >> 2, a = t & 3;
        int j = idx_sh[e];
        long bb = (long)(b0 + j) * 42 + a * 3;
        float* d = &xj_s[e][a * 3];
        d[0] = X[bb];
        d[1] = X[bb + 1];
        d[2] = X[bb + 2];
    } else if (t < 196) {
        int a = t - 192;
        long bb = (long)row * 42 + a * 3;
        xi_s[a * 3 + 0] = X[bb];
        xi_s[a * 3 + 1] = X[bb + 1];
        xi_s[a * 3 + 2] = X[bb + 2];
    }
    if (t < 48) {
        int j = idx_sh[t];
        int off = ridx[row] - ridx[b0 + j] + 32;
        dclip[t] = off < 0 ? 0 : (off > 64 ? 64 : off);
    }
    __syncthreads();
    // virtual atom from LDS (Xc=atom1, X1=atom0, X2=atom2)
    if (t < 49) {
        float* d = (t < 48) ? xj_s[t] : xi_s;
        float cx = d[3], cy = d[4], cz = d[5];
        float b1x = d[0] - cx, b1y = d[1] - cy, b1z = d[2] - cz;
        float b2x = d[6] - cx, b2y = d[7] - cy, b2z = d[8] - cz;
        float nx = b1y * b2z - b1z * b2y;
        float ny = b1z * b2x - b1x * b2z;
        float nz = b1x * b2y - b1y * b2x;
        const float WN = 0.58273431f, WB1 = -0.56802827f, WB2 = -0.54067466f;
        d[12] = WN * nx + WB1 * b1x + WB2 * b2x + cx;
        d[13] = WN * ny + WB1 * b1y + WB2 * b2y + cy;
        d[14] = WN * nz + WB1 * b1z + WB2 * b2z + cz;
    }
    __syncthreads();

    // pos features: f 0..15
    for (int s5 = t; s5 < 48 * 16; s5 += 256) {
        int e = s5 >> 4, f = s5 & 15;
        featbf[e * FPAD + f] = __float2bfloat16(posW[dclip[e] * 16 + f] + posb[f]);
    }
    // RBF: per (e,pq) one D; 16 rbf = 2^(-((D-2)*0.96089793 - 1.2811972*r)^2)
    for (int s5 = t; s5 < 48 * 25; s5 += 256) {
        int e = s5 / 25, pq = s5 - e * 25;
        int ai = pq / 5, aj = pq - ai * 5;
        float dx = xi_s[ai * 3 + 0] - xj_s[e][aj * 3 + 0];
        float dy = xi_s[ai * 3 + 1] - xj_s[e][aj * 3 + 1];
        float dz = xi_s[ai * 3 + 2] - xj_s[e][aj * 3 + 2];
        float D = sqrtf((dx * dx + dy * dy) + dz * dz + 1e-6f);
        float x0c = (D - 2.0f) * 0.96089793f;
        union { short8 v[2]; __hip_bfloat16 h[16]; } u;
#pragma unroll
        for (int rr = 0; rr < 16; ++rr) {
            float xc = x0c - 1.2811972f * (float)rr;
            float ex;
            asm("v_exp_f32 %0, %1" : "=v"(ex) : "v"(-xc * xc));
            u.h[rr] = __float2bfloat16(ex);
        }
        short8* dst = (short8*)&featbf[e * FPAD + 16 + pq * 16];
        dst[0] = u.v[0];
        dst[1] = u.v[1];
    }
    __syncthreads();

    // ---- MFMA: (48 x 416) x (416 x 128), B pre-fetched in registers ----
    const int li = lane & 15, lg = lane >> 4;
    f32x4 acc[3][2];
#pragma unroll
    for (int m = 0; m < 3; ++m)
#pragma unroll
        for (int nn = 0; nn < 2; ++nn) acc[m][nn] = (f32x4){0.f, 0.f, 0.f, 0.f};

    const short8* featv = (const short8*)featbf;
#pragma unroll
    for (int s = 0; s < 13; ++s) {
        short8 afr[3];
#pragma unroll
        for (int m = 0; m < 3; ++m)
            afr[m] = featv[(m * 16 + li) * (FPAD / 8) + s * 4 + lg];
#pragma unroll
        for (int m = 0; m < 3; ++m) {
            acc[m][0] = __builtin_amdgcn_mfma_f32_16x16x32_bf16(
                afr[m], bfrAll[s], acc[m][0], 0, 0, 0);
            acc[m][1] = __builtin_amdgcn_mfma_f32_16x16x32_bf16(
                afr[m], bfrAll[13 + s], acc[m][1], 0, 0, 0);
        }
    }
    __syncthreads();  // featbf dead; alias as accLDS

    // C/D layout: col = lane&15, row = (lane>>4)*4 + r
#pragma unroll
    for (int m = 0; m < 3; ++m)
#pragma unroll
        for (int nn = 0; nn < 2; ++nn)
#pragma unroll
            for (int r = 0; r < 4; ++r) {
                int e = m * 16 + lg * 4 + r;
                int c = (wv * 2 + nn) * 16 + li;
                accLDS[e * CPAD + c] = acc[m][nn][r];
            }
    __syncthreads();

    // LayerNorm partials (vectorized)
    if (t < 192) {
        int e = t >> 2, q = t & 3;
        const f32x4* rp = (const f32x4*)&accLDS[e * CPAD + q * 32];
        float s1 = 0.f, s2 = 0.f;
#pragma unroll
        for (int i = 0; i < 8; ++i) {
            f32x4 v = rp[i];
#pragma unroll
            for (int j = 0; j < 4; ++j) {
                s1 += v[j];
                s2 = fmaf(v[j], v[j], s2);
            }
        }
        ps[e][q] = s1;
        ps2[e][q] = s2;
    }
    __syncthreads();
    if (t < 48) {
        float S = (ps[t][0] + ps[t][1]) + (ps[t][2] + ps[t][3]);
        float S2 = (ps2[t][0] + ps2[t][1]) + (ps2[t][2] + ps2[t][3]);
        float m = S * (1.0f / 128.0f);
        float var = S2 * (1.0f / 128.0f) - m * m;
        mean_s[t] = m;
        inv_s[t] = rsqrtf(var + 1e-5f);
    }
    __syncthreads();

    // normalize + store, float4
    const int cg = (t & 31) * 4;
    const float4 gm4 = *(const float4*)&gamma[cg];
    const float4 bt4 = *(const float4*)&beta[cg];
    const long base = (long)row * (KNB * 128);
    for (int s5 = t; s5 < 48 * 32; s5 += 256) {
        int e = s5 >> 5;
        f32x4 v = *(const f32x4*)&accLDS[e * CPAD + cg];
        float mn = mean_s[e], iv = inv_s[e];
        float4 o;
        o.x = (v[0] - mn) * iv * gm4.x + bt4.x;
        o.y = (v[1] - mn) * iv * gm4.y + bt4.y;
        o.z = (v[2] - mn) * iv * gm4.z + bt4.z;
        o.w = (v[3] - mn) * iv * gm4.w + bt4.w;
        *(float4*)&outE[base + e * 128 + cg] = o;
    }
}

extern "C" void kernel_launch(void* const* d_in, const int* in_sizes, int n_in,
                              void* d_out, int out_size, void* d_ws, size_t ws_size,
                              hipStream_t stream) {
    const float* X = (const float*)d_in[0];
    const float* Xm = (const float*)d_in[1];
    // d_in[2] = S : dead input (slot tables are token-independent)
    const int* ridx = (const int*)d_in[3];
    const float* posW = (const float*)d_in[4];
    const float* posb = (const float*)d_in[5];
    const float* edgeW = (const float*)d_in[6];
    const float* gamma = (const float*)d_in[7];
    const float* beta = (const float*)d_in[8];

    float* out = (float*)d_out;
    const long E_elems = (long)BATCH * LSEQ * KNB * 128;  // 25,165,824
    float* out_idx = out + E_elems;

    // ws: [0, 106496) Bp bf16 B-fragments; [106496, +64KiB) Xc4 float4
    short8* Bp = (short8*)d_ws;
    float4* Xc4 = (float4*)((char*)d_ws + 106496);

    pack_kernel<<<168, 64, 0, stream>>>(edgeW, Bp, X, Xm, Xc4);
    fused_kernel<<<BATCH * LSEQ, 256, 0, stream>>>(X, ridx, posW, posb, Bp, gamma,
                                                   beta, Xc4, out, out_idx);
}

// Round 7
// 87.965 us; speedup vs baseline: 7.3557x; 1.0872x over previous
//
#include <hip/hip_runtime.h>
#include <hip/hip_bf16.h>

#define LSEQ 2048
#define BATCH 2
#define KNB 48

typedef unsigned long long u64;
typedef __attribute__((ext_vector_type(8))) short short8;
typedef __attribute__((ext_vector_type(4))) float f32x4;

// wave-0 helper: find first bin with cum >= K over 256-bin hist; out={bin, below}
__device__ __forceinline__ void scan_find(const int* hist, int K, int* out,
                                          int lane) {
    int bb = lane * 4;
    int c0 = hist[bb], c1 = hist[bb + 1], c2 = hist[bb + 2], c3 = hist[bb + 3];
    int s = c0 + c1 + c2 + c3;
    int inc = s;
#pragma unroll
    for (int off = 1; off < 64; off <<= 1) {
        int o = __shfl_up(inc, off, 64);
        if (lane >= off) inc += o;
    }
    int prev = inc - s;
    int cc[4] = {c0, c1, c2, c3};
#pragma unroll
    for (int j2 = 0; j2 < 4; ++j2) {
        int cum = prev + cc[j2];
        if (prev < K && cum >= K) {
            out[0] = bb + j2;
            out[1] = prev;
        }
        prev = cum;
    }
}

// Pack edgeW into bf16 B-fragments (blocks 0..103) + Xc/mask float4 (104..167)
__global__ __launch_bounds__(64) void pack_kernel(const float* __restrict__ edgeW,
                                                  short8* __restrict__ Bp,
                                                  const float* __restrict__ X,
                                                  const float* __restrict__ Xm,
                                                  float4* __restrict__ Xc4) {
    int blk = blockIdx.x;
    int l = threadIdx.x;
    if (blk < 104) {
        int col = ((blk / 13) * 16) + (l & 15);
        int k0 = (blk % 13) * 32 + (l >> 4) * 8;
        union { short8 v; __hip_bfloat16 h[8]; } u;
#pragma unroll
        for (int j = 0; j < 8; ++j)
            u.h[j] = __float2bfloat16(edgeW[(k0 + j) * 128 + col]);
        Bp[(long)blk * 64 + l] = u.v;
    } else {
        int i = (blk - 104) * 64 + l;  // 0..4095
        long base = (long)i * 42 + 3;  // atom 1
        float4 p;
        p.x = X[base];
        p.y = X[base + 1];
        p.z = X[base + 2];
        p.w = Xm[(long)i * 14 + 1];
        Xc4[i] = p;
    }
}

// One block per row: radix-select top-48 -> features (k-split) -> MFMA -> LN.
__global__ __launch_bounds__(256, 4) void fused_kernel(
    const float* __restrict__ X, const int* __restrict__ ridx,
    const float* __restrict__ posW, const float* __restrict__ posb,
    const short8* __restrict__ Bp, const float* __restrict__ gamma,
    const float* __restrict__ beta, const float4* __restrict__ Xc4,
    float* __restrict__ outE, float* __restrict__ out_idx) {
    // Overlay region: phase-A scratch | feat half-buffer | LN partials
    __shared__ __align__(16) char ovbuf[28 * 768];  // 21,504 B
    __shared__ float xi_s[15];
    __shared__ float xj_s[48][15];
    __shared__ int dclip[48];
    __shared__ int idx_sh[KNB];
    __shared__ float mean_s[48], inv_s[48];

    int* hist1 = (int*)ovbuf;            // 1024 B
    int* hist2 = (int*)(ovbuf + 1024);   // 1024 B
    u64* selA = (u64*)(ovbuf + 2048);    // 512 B
    u64* candA = (u64*)(ovbuf + 2560);   // 512 B
    int* cnts = (int*)(ovbuf + 3072);    // 8 B
    int* scanA = (int*)(ovbuf + 3080);
    int* scanB = (int*)(ovbuf + 3088);
    short8* fw = (short8*)ovbuf;         // feat: [slice][48 edges] of 16B
    float* psp = (float*)ovbuf;          // LN: [48][4]
    float* ps2p = (float*)(ovbuf + 768);

    const int row = blockIdx.x;
    const int b = row >> 11;
    const int t = threadIdx.x;
    const int wv = t >> 6;
    const int lane = t & 63;
    const int li = lane & 15, lg = lane >> 4;
    const int b0 = b << 11;

    // gamma/beta for this lane's two columns (issue early, L2-hot)
    const float gm0 = gamma[wv * 32 + li], gm1 = gamma[wv * 32 + 16 + li];
    const float bt0 = beta[wv * 32 + li], bt1 = beta[wv * 32 + 16 + li];

    // ---- Phase A: top-48 via 2-pass radix select on u64 keys ----
    u64 K[8];
    {
        float4 pjv[8];
#pragma unroll
        for (int kk = 0; kk < 8; ++kk) pjv[kk] = Xc4[b0 + t + kk * 256];
        float4 pi = Xc4[row];
        const float xi0 = pi.x, xi1 = pi.y, xi2 = pi.z, mi = pi.w;
#pragma unroll
        for (int kk = 0; kk < 8; ++kk) {
            int j = t + kk * 256;
            float dx = xi0 - pjv[kk].x, dy = xi1 - pjv[kk].y, dz = xi2 - pjv[kk].z;
            // match numpy exactly: ((dx^2+dy^2)+dz^2)+1e-6, no fma contraction
            float d2 = __fadd_rn(__fadd_rn(__fmul_rn(dx, dx), __fmul_rn(dy, dy)),
                                 __fmul_rn(dz, dz));
            float D = sqrtf(__fadd_rn(d2, 1e-6f));
            float da = D + (1.0f - mi * pjv[kk].w) * 1000000.0f;
            K[kk] = ((u64)__float_as_uint(da) << 32) | (unsigned)j;
        }
    }

    hist1[t] = 0;
    hist2[t] = 0;
    if (t == 0) { cnts[0] = 0; cnts[1] = 0; }
    __syncthreads();
#pragma unroll
    for (int kk = 0; kk < 8; ++kk) atomicAdd(&hist1[(int)(K[kk] >> 56)], 1);
    __syncthreads();
    if (wv == 0) scan_find(hist1, KNB, scanA, lane);
    __syncthreads();
    const int B1 = scanA[0];
    const int need1 = KNB - scanA[1];
#pragma unroll
    for (int kk = 0; kk < 8; ++kk)
        if ((int)(K[kk] >> 56) == B1)
            atomicAdd(&hist2[(int)((K[kk] >> 48) & 0xFF)], 1);
    __syncthreads();
    if (wv == 0) scan_find(hist2, need1, scanB, lane);
    __syncthreads();
    const unsigned T16 = ((unsigned)B1 << 8) | (unsigned)scanB[0];
    const int selbase = (KNB - need1) + scanB[1];
    const int need2 = KNB - selbase;
#pragma unroll
    for (int kk = 0; kk < 8; ++kk) {
        unsigned k16 = (unsigned)(K[kk] >> 48);
        if (k16 < T16) {
            int p = atomicAdd(&cnts[0], 1);
            selA[p] = K[kk];
        } else if (k16 == T16) {
            int p = atomicAdd(&cnts[1], 1);
            if (p < 64) candA[p] = K[kk];
        }
    }
    __syncthreads();
    {
        int candcnt = cnts[1] < 64 ? cnts[1] : 64;
        if (t < 64) {
            bool valid = t < candcnt;
            u64 key = valid ? candA[t] : ~0ULL;
            int rank = 0;
            for (int j = 0; j < candcnt; ++j) rank += (candA[j] < key);
            if (valid && rank < need2) selA[selbase + rank] = key;
        }
    }
    __syncthreads();
    if (t < KNB) {
        u64 key = selA[t];
        int rank = 0;
#pragma unroll
        for (int j = 0; j < KNB; ++j) rank += (selA[j] < key);
        int wi = (int)(key & 0xffffffffu);
        idx_sh[rank] = wi;
        out_idx[(long)row * KNB + rank] = (float)wi;
    }
    __syncthreads();  // idx_sh ready (phase-A scratch dead after this)

    // ---- Phase B: parallel neighbor-atom gather ----
    if (t < 192) {
        int e = t >> 2, a = t & 3;
        int j = idx_sh[e];
        long bb = (long)(b0 + j) * 42 + a * 3;
        float* d = &xj_s[e][a * 3];
        d[0] = X[bb];
        d[1] = X[bb + 1];
        d[2] = X[bb + 2];
    } else if (t < 196) {
        int a = t - 192;
        long bb = (long)row * 42 + a * 3;
        xi_s[a * 3 + 0] = X[bb];
        xi_s[a * 3 + 1] = X[bb + 1];
        xi_s[a * 3 + 2] = X[bb + 2];
    }
    if (t < 48) {
        int j = idx_sh[t];
        int off = ridx[row] - ridx[b0 + j] + 32;
        dclip[t] = off < 0 ? 0 : (off > 64 ? 64 : off);
    }
    __syncthreads();
    // virtual atom (Xc=atom1, X1=atom0, X2=atom2)
    if (t < 49) {
        float* d = (t < 48) ? xj_s[t] : xi_s;
        float cx = d[3], cy = d[4], cz = d[5];
        float b1x = d[0] - cx, b1y = d[1] - cy, b1z = d[2] - cz;
        float b2x = d[6] - cx, b2y = d[7] - cy, b2z = d[8] - cz;
        float nx = b1y * b2z - b1z * b2y;
        float ny = b1z * b2x - b1x * b2z;
        float nz = b1x * b2y - b1y * b2x;
        const float WN = 0.58273431f, WB1 = -0.56802827f, WB2 = -0.54067466f;
        d[12] = WN * nx + WB1 * b1x + WB2 * b2x + cx;
        d[13] = WN * ny + WB1 * b1y + WB2 * b2y + cy;
        d[14] = WN * nz + WB1 * b1z + WB2 * b2z + cz;
    }
    __syncthreads();

    // RBF helper: 16 rbf = 2^(-((D-2)*0.96089793 - 1.2811972*r)^2), two 16B writes
#define RBF_TASK(e_, pq_, g0_)                                                  \
    {                                                                           \
        int ai = (pq_) / 5, aj = (pq_) - ai * 5;                                \
        float dx = xi_s[ai * 3 + 0] - xj_s[e_][aj * 3 + 0];                     \
        float dy = xi_s[ai * 3 + 1] - xj_s[e_][aj * 3 + 1];                     \
        float dz = xi_s[ai * 3 + 2] - xj_s[e_][aj * 3 + 2];                     \
        float D = sqrtf((dx * dx + dy * dy) + dz * dz + 1e-6f);                 \
        float x0c = (D - 2.0f) * 0.96089793f;                                   \
        union { short8 v[2]; __hip_bfloat16 h[16]; } u;                         \
        _Pragma("unroll") for (int rr = 0; rr < 16; ++rr) {                     \
            float xc = x0c - 1.2811972f * (float)rr;                            \
            float ex;                                                           \
            asm("v_exp_f32 %0, %1" : "=v"(ex) : "v"(-xc * xc));                 \
            u.h[rr] = __float2bfloat16(ex);                                     \
        }                                                                       \
        fw[(g0_)*48 + (e_)] = u.v[0];                                           \
        fw[((g0_) + 1) * 48 + (e_)] = u.v[1];                                   \
    }

    // ---- Half A features: pos (slices 0,1) + pq 0..12 (slices 2..27) ----
    for (int s5 = t; s5 < 720; s5 += 256) {
        int e = s5 % 48;
        int u5 = s5 / 48;
        if (u5 < 2) {
            const float4* pw = (const float4*)&posW[dclip[e] * 16 + u5 * 8];
            const float4* pb = (const float4*)&posb[u5 * 8];
            float4 w0 = pw[0], w1 = pw[1], b0v = pb[0], b1v = pb[1];
            union { short8 v; __hip_bfloat16 h[8]; } uu;
            uu.h[0] = __float2bfloat16(w0.x + b0v.x);
            uu.h[1] = __float2bfloat16(w0.y + b0v.y);
            uu.h[2] = __float2bfloat16(w0.z + b0v.z);
            uu.h[3] = __float2bfloat16(w0.w + b0v.w);
            uu.h[4] = __float2bfloat16(w1.x + b1v.x);
            uu.h[5] = __float2bfloat16(w1.y + b1v.y);
            uu.h[6] = __float2bfloat16(w1.z + b1v.z);
            uu.h[7] = __float2bfloat16(w1.w + b1v.w);
            fw[u5 * 48 + e] = uu.v;
        } else {
            int pq = u5 - 2;
            RBF_TASK(e, pq, 2 + 2 * pq)
        }
    }
    __syncthreads();

    // ---- MFMA half A: s = 0..6 (local slices s*4+lg) ----
    f32x4 acc[3][2];
#pragma unroll
    for (int m = 0; m < 3; ++m)
#pragma unroll
        for (int nn = 0; nn < 2; ++nn) acc[m][nn] = (f32x4){0.f, 0.f, 0.f, 0.f};

    const short8* fv = (const short8*)ovbuf;
#pragma unroll
    for (int s = 0; s < 7; ++s) {
        int sl = (s * 4 + lg) * 48;
        short8 a0 = fv[sl + li];
        short8 a1 = fv[sl + 16 + li];
        short8 a2 = fv[sl + 32 + li];
        short8 bq0 = Bp[((wv * 2 + 0) * 13 + s) * 64 + lane];
        short8 bq1 = Bp[((wv * 2 + 1) * 13 + s) * 64 + lane];
        acc[0][0] = __builtin_amdgcn_mfma_f32_16x16x32_bf16(a0, bq0, acc[0][0], 0, 0, 0);
        acc[0][1] = __builtin_amdgcn_mfma_f32_16x16x32_bf16(a0, bq1, acc[0][1], 0, 0, 0);
        acc[1][0] = __builtin_amdgcn_mfma_f32_16x16x32_bf16(a1, bq0, acc[1][0], 0, 0, 0);
        acc[1][1] = __builtin_amdgcn_mfma_f32_16x16x32_bf16(a1, bq1, acc[1][1], 0, 0, 0);
        acc[2][0] = __builtin_amdgcn_mfma_f32_16x16x32_bf16(a2, bq0, acc[2][0], 0, 0, 0);
        acc[2][1] = __builtin_amdgcn_mfma_f32_16x16x32_bf16(a2, bq1, acc[2][1], 0, 0, 0);
    }
    __syncthreads();  // all waves done reading half A

    // ---- Half B features: pq 13..24 (local slices 0..23) ----
    for (int s5 = t; s5 < 576; s5 += 256) {
        int e = s5 % 48;
        int pq = 13 + s5 / 48;
        RBF_TASK(e, pq, 2 * pq - 26)
    }
    __syncthreads();

    // ---- MFMA half B: s = 7..12 (local slices (s-7)*4+lg) ----
#pragma unroll
    for (int s = 7; s < 13; ++s) {
        int sl = ((s - 7) * 4 + lg) * 48;
        short8 a0 = fv[sl + li];
        short8 a1 = fv[sl + 16 + li];
        short8 a2 = fv[sl + 32 + li];
        short8 bq0 = Bp[((wv * 2 + 0) * 13 + s) * 64 + lane];
        short8 bq1 = Bp[((wv * 2 + 1) * 13 + s) * 64 + lane];
        acc[0][0] = __builtin_amdgcn_mfma_f32_16x16x32_bf16(a0, bq0, acc[0][0], 0, 0, 0);
        acc[0][1] = __builtin_amdgcn_mfma_f32_16x16x32_bf16(a0, bq1, acc[0][1], 0, 0, 0);
        acc[1][0] = __builtin_amdgcn_mfma_f32_16x16x32_bf16(a1, bq0, acc[1][0], 0, 0, 0);
        acc[1][1] = __builtin_amdgcn_mfma_f32_16x16x32_bf16(a1, bq1, acc[1][1], 0, 0, 0);
        acc[2][0] = __builtin_amdgcn_mfma_f32_16x16x32_bf16(a2, bq0, acc[2][0], 0, 0, 0);
        acc[2][1] = __builtin_amdgcn_mfma_f32_16x16x32_bf16(a2, bq1, acc[2][1], 0, 0, 0);
    }
    __syncthreads();  // feat dead; overlay becomes LN partials

    // ---- LayerNorm: in-register partials via shfl over li bits ----
    // C/D layout: col = lane&15, row = (lane>>4)*4 + r; edge e = m*16+lg*4+r
#pragma unroll
    for (int m = 0; m < 3; ++m)
#pragma unroll
        for (int r = 0; r < 4; ++r) {
            float v0 = acc[m][0][r], v1 = acc[m][1][r];
            float s1 = v0 + v1;
            float s2 = v0 * v0 + v1 * v1;
#pragma unroll
            for (int off = 1; off < 16; off <<= 1) {
                s1 += __shfl_xor(s1, off, 64);
                s2 += __shfl_xor(s2, off, 64);
            }
            if (li == 0) {
                int e = m * 16 + lg * 4 + r;
                psp[e * 4 + wv] = s1;
                ps2p[e * 4 + wv] = s2;
            }
        }
    __syncthreads();
    if (t < 48) {
        f32x4 p1 = *(const f32x4*)&psp[t * 4];
        f32x4 p2 = *(const f32x4*)&ps2p[t * 4];
        float S = (p1[0] + p1[1]) + (p1[2] + p1[3]);
        float S2 = (p2[0] + p2[1]) + (p2[2] + p2[3]);
        float mn = S * (1.0f / 128.0f);
        float var = S2 * (1.0f / 128.0f) - mn * mn;
        mean_s[t] = mn;
        inv_s[t] = rsqrtf(var + 1e-5f);
    }
    __syncthreads();

    // ---- normalize in-register + store ----
    const long base = (long)row * (KNB * 128);
#pragma unroll
    for (int m = 0; m < 3; ++m)
#pragma unroll
        for (int r = 0; r < 4; ++r) {
            int e = m * 16 + lg * 4 + r;
            float mn = mean_s[e], iv = inv_s[e];
            long rbase = base + (long)e * 128 + wv * 32 + li;
            outE[rbase] = (acc[m][0][r] - mn) * iv * gm0 + bt0;
            outE[rbase + 16] = (acc[m][1][r] - mn) * iv * gm1 + bt1;
        }
}

extern "C" void kernel_launch(void* const* d_in, const int* in_sizes, int n_in,
                              void* d_out, int out_size, void* d_ws, size_t ws_size,
                              hipStream_t stream) {
    const float* X = (const float*)d_in[0];
    const float* Xm = (const float*)d_in[1];
    // d_in[2] = S : dead input (slot tables are token-independent)
    const int* ridx = (const int*)d_in[3];
    const float* posW = (const float*)d_in[4];
    const float* posb = (const float*)d_in[5];
    const float* edgeW = (const float*)d_in[6];
    const float* gamma = (const float*)d_in[7];
    const float* beta = (const float*)d_in[8];

    float* out = (float*)d_out;
    const long E_elems = (long)BATCH * LSEQ * KNB * 128;  // 25,165,824
    float* out_idx = out + E_elems;

    // ws: [0, 106496) Bp bf16 B-fragments; [106496, +64KiB) Xc4 float4
    short8* Bp = (short8*)d_ws;
    float4* Xc4 = (float4*)((char*)d_ws + 106496);

    pack_kernel<<<168, 64, 0, stream>>>(edgeW, Bp, X, Xm, Xc4);
    fused_kernel<<<BATCH * LSEQ, 256, 0, stream>>>(X, ridx, posW, posb, Bp, gamma,
                                                   beta, Xc4, out, out_idx);
}

// Round 8
// 83.990 us; speedup vs baseline: 7.7038x; 1.0473x over previous
//
#include <hip/hip_runtime.h>
#include <hip/hip_bf16.h>

#define LSEQ 2048
#define BATCH 2
#define KNB 48

typedef unsigned long long u64;
typedef __attribute__((ext_vector_type(8))) short short8;
typedef __attribute__((ext_vector_type(4))) float f32x4;

// wave-0 helper: find first bin with cum >= K over 256-bin hist; out={bin, below}
__device__ __forceinline__ void scan_find(const int* hist, int K, int* out,
                                          int lane) {
    int bb = lane * 4;
    int c0 = hist[bb], c1 = hist[bb + 1], c2 = hist[bb + 2], c3 = hist[bb + 3];
    int s = c0 + c1 + c2 + c3;
    int inc = s;
#pragma unroll
    for (int off = 1; off < 64; off <<= 1) {
        int o = __shfl_up(inc, off, 64);
        if (lane >= off) inc += o;
    }
    int prev = inc - s;
    int cc[4] = {c0, c1, c2, c3};
#pragma unroll
    for (int j2 = 0; j2 < 4; ++j2) {
        int cum = prev + cc[j2];
        if (prev < K && cum >= K) {
            out[0] = bb + j2;
            out[1] = prev;
        }
        prev = cum;
    }
}

// Pack edgeW into bf16 B-fragments (blocks 0..103) + Xc/mask float4 (104..167)
__global__ __launch_bounds__(64) void pack_kernel(const float* __restrict__ edgeW,
                                                  short8* __restrict__ Bp,
                                                  const float* __restrict__ X,
                                                  const float* __restrict__ Xm,
                                                  float4* __restrict__ Xc4) {
    int blk = blockIdx.x;
    int l = threadIdx.x;
    if (blk < 104) {
        int col = ((blk / 13) * 16) + (l & 15);
        int k0 = (blk % 13) * 32 + (l >> 4) * 8;
        union { short8 v; __hip_bfloat16 h[8]; } u;
#pragma unroll
        for (int j = 0; j < 8; ++j)
            u.h[j] = __float2bfloat16(edgeW[(k0 + j) * 128 + col]);
        Bp[(long)blk * 64 + l] = u.v;
    } else {
        int i = (blk - 104) * 64 + l;  // 0..4095
        long base = (long)i * 42 + 3;  // atom 1
        float4 p;
        p.x = X[base];
        p.y = X[base + 1];
        p.z = X[base + 2];
        p.w = Xm[(long)i * 14 + 1];
        Xc4[i] = p;
    }
}

// One block per row: radix-select top-48 -> features (4-chunk k-split) -> MFMA -> LN.
__global__ __launch_bounds__(256, 8) void fused_kernel(
    const float* __restrict__ X, const int* __restrict__ ridx,
    const float* __restrict__ posW, const float* __restrict__ posb,
    const short8* __restrict__ Bp, const float* __restrict__ gamma,
    const float* __restrict__ beta, const float4* __restrict__ Xc4,
    float* __restrict__ outE, float* __restrict__ out_idx) {
    // Overlay region: phase-A scratch | feat chunk buffer (16 slices) | LN partials
    __shared__ __align__(16) char ovbuf[16 * 768];  // 12,288 B
    __shared__ float xi_s[15];
    __shared__ float xj_s[48][15];
    __shared__ int dclip[48];
    __shared__ int idx_sh[KNB];
    __shared__ float mean_s[48], inv_s[48];

    int* hist1 = (int*)ovbuf;            // 1024 B
    int* hist2 = (int*)(ovbuf + 1024);   // 1024 B
    u64* selA = (u64*)(ovbuf + 2048);    // 512 B
    u64* candA = (u64*)(ovbuf + 2560);   // 512 B
    int* cnts = (int*)(ovbuf + 3072);    // 8 B
    int* scanA = (int*)(ovbuf + 3080);
    int* scanB = (int*)(ovbuf + 3088);
    short8* fw = (short8*)ovbuf;         // feat chunk: [slice][48 edges] of 16B
    float* psp = (float*)ovbuf;          // LN: [48][4]
    float* ps2p = (float*)(ovbuf + 768);

    const int row = blockIdx.x;
    const int b = row >> 11;
    const int t = threadIdx.x;
    const int wv = t >> 6;
    const int lane = t & 63;
    const int li = lane & 15, lg = lane >> 4;
    const int b0 = b << 11;

    // gamma/beta for this lane's two columns (issue early, L2-hot)
    const float gm0 = gamma[wv * 32 + li], gm1 = gamma[wv * 32 + 16 + li];
    const float bt0 = beta[wv * 32 + li], bt1 = beta[wv * 32 + 16 + li];

    // ---- Phase A: top-48 via 2-pass radix select on u64 keys ----
    u64 K[8];
    {
        float4 pjv[8];
#pragma unroll
        for (int kk = 0; kk < 8; ++kk) pjv[kk] = Xc4[b0 + t + kk * 256];
        float4 pi = Xc4[row];
        const float xi0 = pi.x, xi1 = pi.y, xi2 = pi.z, mi = pi.w;
#pragma unroll
        for (int kk = 0; kk < 8; ++kk) {
            int j = t + kk * 256;
            float dx = xi0 - pjv[kk].x, dy = xi1 - pjv[kk].y, dz = xi2 - pjv[kk].z;
            // match numpy exactly: ((dx^2+dy^2)+dz^2)+1e-6, no fma contraction
            float d2 = __fadd_rn(__fadd_rn(__fmul_rn(dx, dx), __fmul_rn(dy, dy)),
                                 __fmul_rn(dz, dz));
            float D = sqrtf(__fadd_rn(d2, 1e-6f));
            float da = D + (1.0f - mi * pjv[kk].w) * 1000000.0f;
            K[kk] = ((u64)__float_as_uint(da) << 32) | (unsigned)j;
        }
    }

    hist1[t] = 0;
    hist2[t] = 0;
    if (t == 0) { cnts[0] = 0; cnts[1] = 0; }
    __syncthreads();
#pragma unroll
    for (int kk = 0; kk < 8; ++kk) atomicAdd(&hist1[(int)(K[kk] >> 56)], 1);
    __syncthreads();
    if (wv == 0) scan_find(hist1, KNB, scanA, lane);
    __syncthreads();
    const int B1 = scanA[0];
    const int need1 = KNB - scanA[1];
#pragma unroll
    for (int kk = 0; kk < 8; ++kk)
        if ((int)(K[kk] >> 56) == B1)
            atomicAdd(&hist2[(int)((K[kk] >> 48) & 0xFF)], 1);
    __syncthreads();
    if (wv == 0) scan_find(hist2, need1, scanB, lane);
    __syncthreads();
    const unsigned T16 = ((unsigned)B1 << 8) | (unsigned)scanB[0];
    const int selbase = (KNB - need1) + scanB[1];
    const int need2 = KNB - selbase;
#pragma unroll
    for (int kk = 0; kk < 8; ++kk) {
        unsigned k16 = (unsigned)(K[kk] >> 48);
        if (k16 < T16) {
            int p = atomicAdd(&cnts[0], 1);
            selA[p] = K[kk];
        } else if (k16 == T16) {
            int p = atomicAdd(&cnts[1], 1);
            if (p < 64) candA[p] = K[kk];
        }
    }
    __syncthreads();
    {
        int candcnt = cnts[1] < 64 ? cnts[1] : 64;
        if (t < 64) {
            bool valid = t < candcnt;
            u64 key = valid ? candA[t] : ~0ULL;
            int rank = 0;
            for (int j = 0; j < candcnt; ++j) rank += (candA[j] < key);
            if (valid && rank < need2) selA[selbase + rank] = key;
        }
    }
    __syncthreads();
    if (t < KNB) {
        u64 key = selA[t];
        int rank = 0;
#pragma unroll
        for (int j = 0; j < KNB; ++j) rank += (selA[j] < key);
        int wi = (int)(key & 0xffffffffu);
        idx_sh[rank] = wi;
        out_idx[(long)row * KNB + rank] = (float)wi;
    }
    __syncthreads();  // idx_sh ready (phase-A scratch dead after this)

    // ---- Phase B: parallel neighbor-atom gather ----
    if (t < 192) {
        int e = t >> 2, a = t & 3;
        int j = idx_sh[e];
        long bb = (long)(b0 + j) * 42 + a * 3;
        float* d = &xj_s[e][a * 3];
        d[0] = X[bb];
        d[1] = X[bb + 1];
        d[2] = X[bb + 2];
    } else if (t < 196) {
        int a = t - 192;
        long bb = (long)row * 42 + a * 3;
        xi_s[a * 3 + 0] = X[bb];
        xi_s[a * 3 + 1] = X[bb + 1];
        xi_s[a * 3 + 2] = X[bb + 2];
    }
    if (t < 48) {
        int j = idx_sh[t];
        int off = ridx[row] - ridx[b0 + j] + 32;
        dclip[t] = off < 0 ? 0 : (off > 64 ? 64 : off);
    }
    __syncthreads();
    // virtual atom (Xc=atom1, X1=atom0, X2=atom2)
    if (t < 49) {
        float* d = (t < 48) ? xj_s[t] : xi_s;
        float cx = d[3], cy = d[4], cz = d[5];
        float b1x = d[0] - cx, b1y = d[1] - cy, b1z = d[2] - cz;
        float b2x = d[6] - cx, b2y = d[7] - cy, b2z = d[8] - cz;
        float nx = b1y * b2z - b1z * b2y;
        float ny = b1z * b2x - b1x * b2z;
        float nz = b1x * b2y - b1y * b2x;
        const float WN = 0.58273431f, WB1 = -0.56802827f, WB2 = -0.54067466f;
        d[12] = WN * nx + WB1 * b1x + WB2 * b2x + cx;
        d[13] = WN * ny + WB1 * b1y + WB2 * b2y + cy;
        d[14] = WN * nz + WB1 * b1z + WB2 * b2z + cz;
    }
    __syncthreads();

    // RBF: 16 rbf = 2^(-((D-2)*0.96089793 - 1.2811972*r)^2); writes at LOCAL g0
#define RBF_TASK(e_, pq_, g0_)                                                  \
    {                                                                           \
        int ai = (pq_) / 5, aj = (pq_) - ai * 5;                                \
        float dx = xi_s[ai * 3 + 0] - xj_s[e_][aj * 3 + 0];                     \
        float dy = xi_s[ai * 3 + 1] - xj_s[e_][aj * 3 + 1];                     \
        float dz = xi_s[ai * 3 + 2] - xj_s[e_][aj * 3 + 2];                     \
        float D = sqrtf((dx * dx + dy * dy) + dz * dz + 1e-6f);                 \
        float x0c = (D - 2.0f) * 0.96089793f;                                   \
        union { short8 v[2]; __hip_bfloat16 h[16]; } u;                         \
        _Pragma("unroll") for (int rr = 0; rr < 16; ++rr) {                     \
            float xc = x0c - 1.2811972f * (float)rr;                            \
            float ex;                                                           \
            asm("v_exp_f32 %0, %1" : "=v"(ex) : "v"(-xc * xc));                 \
            u.h[rr] = __float2bfloat16(ex);                                     \
        }                                                                       \
        fw[(g0_)*48 + (e_)] = u.v[0];                                           \
        fw[((g0_) + 1) * 48 + (e_)] = u.v[1];                                   \
    }

// MFMA over s in [SLO, SHI), chunk slice base BASE
#define MFMA_CHUNK(SLO, SHI, BASE)                                              \
    _Pragma("unroll") for (int s = (SLO); s < (SHI); ++s) {                     \
        int sl = (s * 4 + lg - (BASE)) * 48;                                    \
        short8 a0 = fv[sl + li];                                                \
        short8 a1 = fv[sl + 16 + li];                                           \
        short8 a2 = fv[sl + 32 + li];                                           \
        short8 bq0 = Bp[((wv * 2 + 0) * 13 + s) * 64 + lane];                   \
        short8 bq1 = Bp[((wv * 2 + 1) * 13 + s) * 64 + lane];                   \
        acc[0][0] = __builtin_amdgcn_mfma_f32_16x16x32_bf16(a0, bq0, acc[0][0], 0, 0, 0); \
        acc[0][1] = __builtin_amdgcn_mfma_f32_16x16x32_bf16(a0, bq1, acc[0][1], 0, 0, 0); \
        acc[1][0] = __builtin_amdgcn_mfma_f32_16x16x32_bf16(a1, bq0, acc[1][0], 0, 0, 0); \
        acc[1][1] = __builtin_amdgcn_mfma_f32_16x16x32_bf16(a1, bq1, acc[1][1], 0, 0, 0); \
        acc[2][0] = __builtin_amdgcn_mfma_f32_16x16x32_bf16(a2, bq0, acc[2][0], 0, 0, 0); \
        acc[2][1] = __builtin_amdgcn_mfma_f32_16x16x32_bf16(a2, bq1, acc[2][1], 0, 0, 0); \
    }

    const short8* fv = (const short8*)ovbuf;
    f32x4 acc[3][2];
#pragma unroll
    for (int m = 0; m < 3; ++m)
#pragma unroll
        for (int nn = 0; nn < 2; ++nn) acc[m][nn] = (f32x4){0.f, 0.f, 0.f, 0.f};

    // ---- Chunk 0: slices 0..11 (pos u=0,1 + pq 0..4), MFMA s=0..2 ----
    for (int s5 = t; s5 < 7 * 48; s5 += 256) {
        int e = s5 % 48;
        int u5 = s5 / 48;
        if (u5 < 2) {
            const float4* pw = (const float4*)&posW[dclip[e] * 16 + u5 * 8];
            const float4* pb = (const float4*)&posb[u5 * 8];
            float4 w0 = pw[0], w1 = pw[1], b0v = pb[0], b1v = pb[1];
            union { short8 v; __hip_bfloat16 h[8]; } uu;
            uu.h[0] = __float2bfloat16(w0.x + b0v.x);
            uu.h[1] = __float2bfloat16(w0.y + b0v.y);
            uu.h[2] = __float2bfloat16(w0.z + b0v.z);
            uu.h[3] = __float2bfloat16(w0.w + b0v.w);
            uu.h[4] = __float2bfloat16(w1.x + b1v.x);
            uu.h[5] = __float2bfloat16(w1.y + b1v.y);
            uu.h[6] = __float2bfloat16(w1.z + b1v.z);
            uu.h[7] = __float2bfloat16(w1.w + b1v.w);
            fw[u5 * 48 + e] = uu.v;
        } else {
            int pq = u5 - 2;  // 0..4, global slices 2+2pq,3+2pq (base 0)
            RBF_TASK(e, pq, 2 + 2 * pq)
        }
    }
    __syncthreads();
    MFMA_CHUNK(0, 3, 0)
    __syncthreads();

    // ---- Chunk 1: slices 12..23 (pq 5..10), MFMA s=3..5 ----
    for (int s5 = t; s5 < 6 * 48; s5 += 256) {
        int e = s5 % 48;
        int pq = 5 + s5 / 48;
        RBF_TASK(e, pq, 2 + 2 * pq - 12)
    }
    __syncthreads();
    MFMA_CHUNK(3, 6, 12)
    __syncthreads();

    // ---- Chunk 2: slices 24..35 (pq 11..16), MFMA s=6..8 ----
    for (int s5 = t; s5 < 6 * 48; s5 += 256) {
        int e = s5 % 48;
        int pq = 11 + s5 / 48;
        RBF_TASK(e, pq, 2 + 2 * pq - 24)
    }
    __syncthreads();
    MFMA_CHUNK(6, 9, 24)
    __syncthreads();

    // ---- Chunk 3: slices 36..51 (pq 17..24), MFMA s=9..12 ----
    for (int s5 = t; s5 < 8 * 48; s5 += 256) {
        int e = s5 % 48;
        int pq = 17 + s5 / 48;
        RBF_TASK(e, pq, 2 + 2 * pq - 36)
    }
    __syncthreads();
    MFMA_CHUNK(9, 13, 36)
    __syncthreads();  // feat dead; overlay becomes LN partials

    // ---- LayerNorm: in-register partials via shfl over li bits ----
    // C/D layout: col = lane&15, row = (lane>>4)*4 + r; edge e = m*16+lg*4+r
#pragma unroll
    for (int m = 0; m < 3; ++m)
#pragma unroll
        for (int r = 0; r < 4; ++r) {
            float v0 = acc[m][0][r], v1 = acc[m][1][r];
            float s1 = v0 + v1;
            float s2 = v0 * v0 + v1 * v1;
#pragma unroll
            for (int off = 1; off < 16; off <<= 1) {
                s1 += __shfl_xor(s1, off, 64);
                s2 += __shfl_xor(s2, off, 64);
            }
            if (li == 0) {
                int e = m * 16 + lg * 4 + r;
                psp[e * 4 + wv] = s1;
                ps2p[e * 4 + wv] = s2;
            }
        }
    __syncthreads();
    if (t < 48) {
        f32x4 p1 = *(const f32x4*)&psp[t * 4];
        f32x4 p2 = *(const f32x4*)&ps2p[t * 4];
        float S = (p1[0] + p1[1]) + (p1[2] + p1[3]);
        float S2 = (p2[0] + p2[1]) + (p2[2] + p2[3]);
        float mn = S * (1.0f / 128.0f);
        float var = S2 * (1.0f / 128.0f) - mn * mn;
        mean_s[t] = mn;
        inv_s[t] = rsqrtf(var + 1e-5f);
    }
    __syncthreads();

    // ---- normalize in-register + store ----
    const long base = (long)row * (KNB * 128);
#pragma unroll
    for (int m = 0; m < 3; ++m)
#pragma unroll
        for (int r = 0; r < 4; ++r) {
            int e = m * 16 + lg * 4 + r;
            float mn = mean_s[e], iv = inv_s[e];
            long rbase = base + (long)e * 128 + wv * 32 + li;
            outE[rbase] = (acc[m][0][r] - mn) * iv * gm0 + bt0;
            outE[rbase + 16] = (acc[m][1][r] - mn) * iv * gm1 + bt1;
        }
}

extern "C" void kernel_launch(void* const* d_in, const int* in_sizes, int n_in,
                              void* d_out, int out_size, void* d_ws, size_t ws_size,
                              hipStream_t stream) {
    const float* X = (const float*)d_in[0];
    const float* Xm = (const float*)d_in[1];
    // d_in[2] = S : dead input (slot tables are token-independent)
    const int* ridx = (const int*)d_in[3];
    const float* posW = (const float*)d_in[4];
    const float* posb = (const float*)d_in[5];
    const float* edgeW = (const float*)d_in[6];
    const float* gamma = (const float*)d_in[7];
    const float* beta = (const float*)d_in[8];

    float* out = (float*)d_out;
    const long E_elems = (long)BATCH * LSEQ * KNB * 128;  // 25,165,824
    float* out_idx = out + E_elems;

    // ws: [0, 106496) Bp bf16 B-fragments; [106496, +64KiB) Xc4 float4
    short8* Bp = (short8*)d_ws;
    float4* Xc4 = (float4*)((char*)d_ws + 106496);

    pack_kernel<<<168, 64, 0, stream>>>(edgeW, Bp, X, Xm, Xc4);
    fused_kernel<<<BATCH * LSEQ, 256, 0, stream>>>(X, ridx, posW, posb, Bp, gamma,
                                                   beta, Xc4, out, out_idx);
}